// Round 7
// baseline (8104.253 us; speedup 1.0000x reference)
//
#include <hip/hip_runtime.h>
#include <math.h>

#define D_DIM 1024
#define N_COMP 4096
#define B_ROWS 16384
#define TOPK 8
#define NCAND 16
#define EPSV 1e-8f

// ---------------- workspace layout (in float slots) ----------------
#define WS_MEAN  0         // 1024
#define WS_KNORM 1024      // 4096
#define WS_KNN   5120      // 4096*1024 (bit-exact k_n)
#define WS_CI    4199424   // candidate idx: 16384*16 ints
#define WS_TW    4461568   // softmax weights: 16384*8
#define WS_TI    4592640   // final idx: 16384*8 ints
// total 4723712 floats = 18.9 MB

// ===== numpy npyv (AVX-512) pairwise-sum emulation =====
// (R4 vs R5 proved the contested rows are insensitive to the leaf flavor;
// keep the AVX-512 16-lane variant.)
__device__ __forceinline__ float np_leaf128(const float* __restrict__ x,
                                            const float* __restrict__ m,
                                            int mode) {
    float lane[16];
    #pragma unroll
    for (int l = 0; l < 16; ++l) {
        float p[8];
        #pragma unroll
        for (int j = 0; j < 8; ++j) {
            float e = x[16 * j + l];
            if (mode == 1) e = __fmul_rn(e, m[16 * j + l]);
            p[j] = __fmul_rn(e, e);
        }
        float t0 = __fadd_rn(p[0], p[1]);
        float t1 = __fadd_rn(p[2], p[3]);
        float t2 = __fadd_rn(p[4], p[5]);
        float t3 = __fadd_rn(p[6], p[7]);
        lane[l] = __fadd_rn(__fadd_rn(t0, t1), __fadd_rn(t2, t3));
    }
    float a[8], b[4], c[2];
    #pragma unroll
    for (int l = 0; l < 8; ++l) a[l] = __fadd_rn(lane[l], lane[l + 8]);
    #pragma unroll
    for (int l = 0; l < 4; ++l) b[l] = __fadd_rn(a[l], a[l + 4]);
    #pragma unroll
    for (int l = 0; l < 2; ++l) c[l] = __fadd_rn(b[l], b[l + 2]);
    return __fadd_rn(c[0], c[1]);
}

// numpy pairwise for n=1024: 1024->512->256->128 leaves,
// combine ((L0+L1)+(L2+L3))+((L4+L5)+(L6+L7))
__device__ __forceinline__ float np_norm1024_sq(const float* __restrict__ x,
                                                const float* __restrict__ m,
                                                int mode) {
    float L[8];
    #pragma unroll
    for (int ch = 0; ch < 8; ++ch)
        L[ch] = np_leaf128(x + ch * 128, m ? m + ch * 128 : m, mode);
    return __fadd_rn(
        __fadd_rn(__fadd_rn(L[0], L[1]), __fadd_rn(L[2], L[3])),
        __fadd_rn(__fadd_rn(L[4], L[5]), __fadd_rn(L[6], L[7])));
}

// ---------------- kernel A: np-faithful mean (sequential f32 over N) --------
__global__ void seqmean_kernel(const float* __restrict__ attn,
                               float* __restrict__ mean) {
    int d = blockIdx.x * 256 + threadIdx.x;
    float s = 0.f;
    for (int n = 0; n < N_COMP; ++n)
        s = __fadd_rn(s, attn[(size_t)n * D_DIM + d]);
    mean[d] = __fdiv_rn(s, (float)N_COMP);   // /4096 exact (pow2)
}

// ---------------- kernel B: np-faithful key norms (one thread per row) ------
__global__ void knorm_kernel(const float* __restrict__ keys,
                             float* __restrict__ knorm) {
    int n = blockIdx.x * 256 + threadIdx.x;
    if (n >= N_COMP) return;
    float nk = np_norm1024_sq(keys + (size_t)n * D_DIM, nullptr, 0);
    knorm[n] = fmaxf(__fsqrt_rn(nk), EPSV);
}

// ---------------- kernel C: knn = keys / knorm (bit-exact k_n) --------------
__global__ void knn_kernel(const float* __restrict__ keys,
                           const float* __restrict__ knorm,
                           float* __restrict__ knn) {
    int n = blockIdx.x;
    float kn = knorm[n];
    int d = threadIdx.x * 4;
    const float* row = keys + (size_t)n * D_DIM + d;
    float* orow = knn + (size_t)n * D_DIM + d;
    orow[0] = __fdiv_rn(row[0], kn);
    orow[1] = __fdiv_rn(row[1], kn);
    orow[2] = __fdiv_rn(row[2], kn);
    orow[3] = __fdiv_rn(row[3], kn);
}

// ---------------- kernel D: fused GEMM ((q*mean) @ knn^T) + top-16 ----------
#define BM 64
#define BN 64
#define BK 16

__global__ __launch_bounds__(256) void simtop_kernel(
    const float* __restrict__ q, const float* __restrict__ knn,
    const float* __restrict__ mean, int* __restrict__ candi) {
    __shared__ float qs[BK][BM];
    __shared__ float ks[BK][BN];
    __shared__ float sims[BM][BN + 1];

    int row0 = blockIdx.x * BM;
    int tid = threadIdx.x;
    int tx = tid & 15, ty = tid >> 4;
    int lr = tid >> 2;            // 0..63
    int lk4 = (tid & 3) << 2;     // 0,4,8,12

    float v[NCAND];
    int ix[NCAND];
    #pragma unroll
    for (int s = 0; s < NCAND; ++s) { v[s] = -1e30f; ix[s] = 0; }

    for (int n0 = 0; n0 < N_COMP; n0 += BN) {
        float acc[4][4];
        #pragma unroll
        for (int i = 0; i < 4; ++i)
            #pragma unroll
            for (int j = 0; j < 4; ++j) acc[i][j] = 0.f;

        for (int kk = 0; kk < D_DIM; kk += BK) {
            float4 qv = *(const float4*)(q + (size_t)(row0 + lr) * D_DIM + kk + lk4);
            float4 mv = *(const float4*)(mean + kk + lk4);
            float4 kv = *(const float4*)(knn + (size_t)(n0 + lr) * D_DIM + kk + lk4);
            qv.x *= mv.x; qv.y *= mv.y; qv.z *= mv.z; qv.w *= mv.w;
            __syncthreads();
            qs[lk4 + 0][lr] = qv.x; qs[lk4 + 1][lr] = qv.y;
            qs[lk4 + 2][lr] = qv.z; qs[lk4 + 3][lr] = qv.w;
            ks[lk4 + 0][lr] = kv.x; ks[lk4 + 1][lr] = kv.y;
            ks[lk4 + 2][lr] = kv.z; ks[lk4 + 3][lr] = kv.w;
            __syncthreads();
            #pragma unroll
            for (int k = 0; k < BK; ++k) {
                float4 a = *(const float4*)&qs[k][ty * 4];
                float4 b = *(const float4*)&ks[k][tx * 4];
                acc[0][0] += a.x * b.x; acc[0][1] += a.x * b.y;
                acc[0][2] += a.x * b.z; acc[0][3] += a.x * b.w;
                acc[1][0] += a.y * b.x; acc[1][1] += a.y * b.y;
                acc[1][2] += a.y * b.z; acc[1][3] += a.y * b.w;
                acc[2][0] += a.z * b.x; acc[2][1] += a.z * b.y;
                acc[2][2] += a.z * b.z; acc[2][3] += a.z * b.w;
                acc[3][0] += a.w * b.x; acc[3][1] += a.w * b.y;
                acc[3][2] += a.w * b.z; acc[3][3] += a.w * b.w;
            }
        }
        __syncthreads();
        #pragma unroll
        for (int i = 0; i < 4; ++i) {
            float4 o;
            o.x = acc[i][0]; o.y = acc[i][1]; o.z = acc[i][2]; o.w = acc[i][3];
            *(float4*)&sims[ty * 4 + i][tx * 4] = o;
        }
        __syncthreads();
        if (tid < BM) {
            int r = tid;
            #pragma unroll 1
            for (int c = 0; c < BN; ++c) {
                float cv = sims[r][c];
                if (cv > v[NCAND - 1]) {
                    v[NCAND - 1] = cv; ix[NCAND - 1] = n0 + c;
                    #pragma unroll
                    for (int s = NCAND - 1; s > 0; --s) {
                        if (v[s] > v[s - 1]) {
                            float tv = v[s]; v[s] = v[s - 1]; v[s - 1] = tv;
                            int ti = ix[s]; ix[s] = ix[s - 1]; ix[s - 1] = ti;
                        }
                    }
                }
            }
        }
        __syncthreads();
    }
    if (tid < BM) {
        int gr = row0 + tid;
        #pragma unroll
        for (int s = 0; s < NCAND; ++s)
            candi[gr * NCAND + s] = ix[s];
    }
}

// ---------------- kernel E: OpenBLAS-SKX KC=320 rescore + top-8 + softmax ----
// Per C element: c = chain(0,320); c += chain(320,640); c += chain(640,960);
// c += chain(960,1024). Each chain = sequential f32 FMA (single accumulator).
__global__ __launch_bounds__(256) void rescore_kernel(
    const float* __restrict__ q, const float* __restrict__ knn,
    const float* __restrict__ mean, const int* __restrict__ candi,
    float* __restrict__ topw, int* __restrict__ topi) {
    __shared__ float anbuf[4][D_DIM];
    __shared__ float vbuf[4][NCAND];
    int wave = threadIdx.x >> 6, lane = threadIdx.x & 63;
    int b = blockIdx.x * 4 + wave;
    const float* qr = q + (size_t)b * D_DIM;

    // lane 0: ||aq|| via numpy npyv pairwise of fl(fl(q*m)^2)
    float nqd;
    if (lane == 0) {
        float nq = np_norm1024_sq(qr, mean, 1);
        nqd = fmaxf(__fsqrt_rn(nq), EPSV);
    }
    nqd = __shfl(nqd, 0);

    // all lanes: materialize f32 aq_n (bitwise = numpy's aq / max(norm,eps))
    #pragma unroll
    for (int rep = 0; rep < 16; ++rep) {
        int d = rep * 64 + lane;
        float a = __fmul_rn(qr[d], mean[d]);
        anbuf[wave][d] = __fdiv_rn(a, nqd);
    }
    __syncthreads();

    // lanes 0..15: one candidate each, KC=320 chunked sequential FMA chains
    if (lane < NCAND) {
        int id = candi[b * NCAND + lane];
        const float* kr = knn + (size_t)id * D_DIM;
        const float* an = anbuf[wave];
        float c1 = 0.f, c2 = 0.f, c3 = 0.f, c4 = 0.f;
        #pragma unroll 8
        for (int d = 0; d < 320; ++d)
            c1 = __fmaf_rn(an[d], kr[d], c1);
        #pragma unroll 8
        for (int d = 320; d < 640; ++d)
            c2 = __fmaf_rn(an[d], kr[d], c2);
        #pragma unroll 8
        for (int d = 640; d < 960; ++d)
            c3 = __fmaf_rn(an[d], kr[d], c3);
        #pragma unroll 8
        for (int d = 960; d < 1024; ++d)
            c4 = __fmaf_rn(an[d], kr[d], c4);
        vbuf[wave][lane] =
            __fadd_rn(__fadd_rn(__fadd_rn(c1, c2), c3), c4);
    }
    __syncthreads();

    if (lane == 0) {
        float vals[NCAND];
        int ids[NCAND];
        #pragma unroll
        for (int c = 0; c < NCAND; ++c) {
            vals[c] = vbuf[wave][c];
            ids[c] = candi[b * NCAND + c];
        }
        // top-8, ties -> lower index first
        #pragma unroll
        for (int s = 0; s < TOPK; ++s)
            #pragma unroll
            for (int j = s + 1; j < NCAND; ++j) {
                bool better = (vals[j] > vals[s]) ||
                              (vals[j] == vals[s] && ids[j] < ids[s]);
                if (better) {
                    float tv = vals[s]; vals[s] = vals[j]; vals[j] = tv;
                    int ti = ids[s]; ids[s] = ids[j]; ids[j] = ti;
                }
            }
        float m = vals[0];
        float w[TOPK];
        float ssum = 0.f;
        #pragma unroll
        for (int k = 0; k < TOPK; ++k) { w[k] = expf(vals[k] - m); ssum += w[k]; }
        float rs = 1.0f / ssum;
        #pragma unroll
        for (int k = 0; k < TOPK; ++k) {
            topw[b * TOPK + k] = w[k] * rs;
            topi[b * TOPK + k] = ids[k];
        }
    }
}

// ---------------- kernel F: weighted gather + outputs ------------------------
__global__ void output_kernel(const float* __restrict__ topw,
                              const int* __restrict__ topi,
                              const float* __restrict__ prompts,
                              const float* __restrict__ keys,
                              float* __restrict__ out) {
    int b = blockIdx.x;
    float w[TOPK];
    int id[TOPK];
    #pragma unroll
    for (int k = 0; k < TOPK; ++k) {
        w[k] = topw[b * TOPK + k];
        id[k] = topi[b * TOPK + k];
    }

    const size_t OFF1 = (size_t)B_ROWS * D_DIM;
    const size_t OFF2 = OFF1 + (size_t)B_ROWS * TOPK;

    if (threadIdx.x < TOPK)
        out[OFF1 + (size_t)b * TOPK + threadIdx.x] = (float)id[threadIdx.x];

    int d0 = threadIdx.x * 4;   // 256 threads * 4 = 1024
    float4 acc; acc.x = acc.y = acc.z = acc.w = 0.f;
    #pragma unroll
    for (int k = 0; k < TOPK; ++k) {
        const float* pr = prompts + (size_t)id[k] * D_DIM + d0;
        float4 pv = *(const float4*)pr;
        acc.x += w[k] * pv.x; acc.y += w[k] * pv.y;
        acc.z += w[k] * pv.z; acc.w += w[k] * pv.w;
        const float* kr = keys + (size_t)id[k] * D_DIM + d0;
        float4 kv = *(const float4*)kr;
        *(float4*)(out + OFF2 + ((size_t)b * TOPK + k) * D_DIM + d0) = kv;
    }
    *(float4*)(out + (size_t)b * D_DIM + d0) = acc;
}

// ---------------- launch ----------------
extern "C" void kernel_launch(void* const* d_in, const int* in_sizes, int n_in,
                              void* d_out, int out_size, void* d_ws, size_t ws_size,
                              hipStream_t stream) {
    const float* query   = (const float*)d_in[0];
    const float* prompts = (const float*)d_in[1];
    const float* keys    = (const float*)d_in[2];
    const float* attn    = (const float*)d_in[3];
    float* ws = (float*)d_ws;
    float* out = (float*)d_out;

    float* mean  = ws + WS_MEAN;
    float* knorm = ws + WS_KNORM;
    float* knn   = ws + WS_KNN;
    int*   candi = (int*)(ws + WS_CI);
    float* topw  = ws + WS_TW;
    int*   topi  = (int*)(ws + WS_TI);

    seqmean_kernel<<<4, 256, 0, stream>>>(attn, mean);
    knorm_kernel<<<(N_COMP + 255) / 256, 256, 0, stream>>>(keys, knorm);
    knn_kernel<<<N_COMP, 256, 0, stream>>>(keys, knorm, knn);
    simtop_kernel<<<B_ROWS / BM, 256, 0, stream>>>(query, knn, mean, candi);
    rescore_kernel<<<B_ROWS / 4, 256, 0, stream>>>(query, knn, mean, candi,
                                                   topw, topi);
    output_kernel<<<B_ROWS, 256, 0, stream>>>(topw, topi, prompts, keys, out);
}

// Round 8
// 4806.837 us; speedup vs baseline: 1.6860x; 1.6860x over previous
//
#include <hip/hip_runtime.h>
#include <math.h>

#define D_DIM 1024
#define N_COMP 4096
#define B_ROWS 16384
#define TOPK 8
#define NC_Q 16
#define NCAND 64
#define EPSV 1e-8f

typedef __bf16 bf16x8 __attribute__((ext_vector_type(8)));
typedef float f32x4 __attribute__((ext_vector_type(4)));

// ---------------- workspace layout (in float slots) ----------------
#define WS_MEAN  0         // 1024
#define WS_KNORM 1024      // 4096
#define WS_KNN   5120      // 4096*1024 f32 (bit-exact k_n, rescore input)
#define WS_KN16  4199424   // 4096*1024 bf16 (ushort) = 2097152 float slots
#define WS_CI    6296576   // candidate idx: 16384*64 ints
#define WS_TW    7345152   // softmax weights: 16384*8
#define WS_TI    7476224   // final idx: 16384*8 ints
// total 7607296 floats = 30.4 MB

__device__ __forceinline__ unsigned short bf16rne(float f) {
    unsigned int u = __float_as_uint(f);
    return (unsigned short)((u + 0x7FFFu + ((u >> 16) & 1u)) >> 16);
}

__device__ __forceinline__ void gload16(const void* g, void* l) {
    __builtin_amdgcn_global_load_lds(
        (const __attribute__((address_space(1))) void*)g,
        (__attribute__((address_space(3))) void*)l, 16, 0, 0);
}

// ===== numpy npyv pairwise-sum emulation (PASSED in R7 — frozen) =====
__device__ __forceinline__ float np_leaf128(const float* __restrict__ x,
                                            const float* __restrict__ m,
                                            int mode) {
    float lane[16];
    #pragma unroll
    for (int l = 0; l < 16; ++l) {
        float p[8];
        #pragma unroll
        for (int j = 0; j < 8; ++j) {
            float e = x[16 * j + l];
            if (mode == 1) e = __fmul_rn(e, m[16 * j + l]);
            p[j] = __fmul_rn(e, e);
        }
        float t0 = __fadd_rn(p[0], p[1]);
        float t1 = __fadd_rn(p[2], p[3]);
        float t2 = __fadd_rn(p[4], p[5]);
        float t3 = __fadd_rn(p[6], p[7]);
        lane[l] = __fadd_rn(__fadd_rn(t0, t1), __fadd_rn(t2, t3));
    }
    float a[8], b[4], c[2];
    #pragma unroll
    for (int l = 0; l < 8; ++l) a[l] = __fadd_rn(lane[l], lane[l + 8]);
    #pragma unroll
    for (int l = 0; l < 4; ++l) b[l] = __fadd_rn(a[l], a[l + 4]);
    #pragma unroll
    for (int l = 0; l < 2; ++l) c[l] = __fadd_rn(b[l], b[l + 2]);
    return __fadd_rn(c[0], c[1]);
}

__device__ __forceinline__ float np_norm1024_sq(const float* __restrict__ x,
                                                const float* __restrict__ m,
                                                int mode) {
    float L[8];
    #pragma unroll
    for (int ch = 0; ch < 8; ++ch)
        L[ch] = np_leaf128(x + ch * 128, m ? m + ch * 128 : m, mode);
    return __fadd_rn(
        __fadd_rn(__fadd_rn(L[0], L[1]), __fadd_rn(L[2], L[3])),
        __fadd_rn(__fadd_rn(L[4], L[5]), __fadd_rn(L[6], L[7])));
}

// ---------------- kernel A: np-faithful mean (frozen bits, +unroll) ---------
__global__ void seqmean_kernel(const float* __restrict__ attn,
                               float* __restrict__ mean) {
    int d = blockIdx.x * 256 + threadIdx.x;
    float s = 0.f;
    #pragma unroll 16
    for (int n = 0; n < N_COMP; ++n)
        s = __fadd_rn(s, attn[(size_t)n * D_DIM + d]);
    mean[d] = __fdiv_rn(s, (float)N_COMP);
}

// ---------------- kernel B: np-faithful key norms (frozen) ------------------
__global__ void knorm_kernel(const float* __restrict__ keys,
                             float* __restrict__ knorm) {
    int n = blockIdx.x * 256 + threadIdx.x;
    if (n >= N_COMP) return;
    float nk = np_norm1024_sq(keys + (size_t)n * D_DIM, nullptr, 0);
    knorm[n] = fmaxf(__fsqrt_rn(nk), EPSV);
}

// ---------------- kernel C: knn f32 (frozen bits) + bf16 copy ---------------
__global__ void knn_kernel(const float* __restrict__ keys,
                           const float* __restrict__ knorm,
                           float* __restrict__ knn,
                           unsigned short* __restrict__ kn16) {
    int n = blockIdx.x;
    float kn = knorm[n];
    int d = threadIdx.x * 4;
    const float* row = keys + (size_t)n * D_DIM + d;
    float* orow = knn + (size_t)n * D_DIM + d;
    unsigned short* o16 = kn16 + (size_t)n * D_DIM + d;
    float r0 = __fdiv_rn(row[0], kn);
    float r1 = __fdiv_rn(row[1], kn);
    float r2 = __fdiv_rn(row[2], kn);
    float r3 = __fdiv_rn(row[3], kn);
    orow[0] = r0; orow[1] = r1; orow[2] = r2; orow[3] = r3;
    o16[0] = bf16rne(r0); o16[1] = bf16rne(r1);
    o16[2] = bf16rne(r2); o16[3] = bf16rne(r3);
}

// ---------------- kernel D: MFMA bf16 GEMM + per-quarter top-16 -------------
// grid = 128 row-blocks x 4 col-quarters. Block: 128 rows x 1024 cols,
// looping 8 col-tiles of 128. BK=64, 4 waves (2x2), 16x16x32 bf16 MFMA.
// LDS slots (16B) XOR-swizzled by (row&7): conflict-free ds_read_b128.
__global__ __launch_bounds__(256, 2) void simtop_mfma(
    const float* __restrict__ qf, const float* __restrict__ mean,
    const unsigned short* __restrict__ kn16, int* __restrict__ candi) {
    __shared__ __align__(16) char RAW[65536];
    uint4* A4 = (uint4*)RAW;               // [128 rows][8 slots]
    uint4* B4 = (uint4*)(RAW + 16384);     // [128 cols][8 slots]
    float* SIM = (float*)(RAW + 31744);    // [64][129], overlays B4 tail (dead)

    const int tid = threadIdx.x;
    const int lane = tid & 63;
    const int wid = tid >> 6;
    const int wr = wid >> 1, wc = wid & 1;
    const int l15 = lane & 15, l4 = lane >> 4;
    const int rb = blockIdx.x >> 2;
    const int qq = blockIdx.x & 3;
    const int row0 = rb * 128;
    const int colQ = qq * 1024;

    float v[NC_Q]; int ix[NC_Q];
    #pragma unroll
    for (int s = 0; s < NC_Q; ++s) { v[s] = -1e30f; ix[s] = 0; }

    const int br = tid >> 3, bj = tid & 7;       // B staging map
    const int ar = tid >> 1, akb = (tid & 1) * 32; // A staging map

    for (int ct = 0; ct < 8; ++ct) {
        const int col0 = colQ + ct * 128;
        f32x4 acc[4][4];
        #pragma unroll
        for (int i = 0; i < 4; ++i)
            #pragma unroll
            for (int j = 0; j < 4; ++j) {
                acc[i][j][0] = 0.f; acc[i][j][1] = 0.f;
                acc[i][j][2] = 0.f; acc[i][j][3] = 0.f;
            }

        for (int kt = 0; kt < 16; ++kt) {
            const int k0 = kt * 64;
            __syncthreads();
            // B: global_load_lds, source pre-swizzled (slot ^ (row&7))
            #pragma unroll
            for (int c = 0; c < 4; ++c) {
                int r = c * 32 + br;
                int jg = bj ^ (r & 7);
                gload16(kn16 + (size_t)(col0 + r) * D_DIM + k0 + jg * 8,
                        (char*)B4 + c * 4096 + tid * 16);
            }
            // A: reg-staged q*mean -> bf16, swizzled ds_write
            {
                const float* qrow = qf + (size_t)(row0 + ar) * D_DIM + k0 + akb;
                const float* mrow = mean + k0 + akb;
                #pragma unroll
                for (int j = 0; j < 4; ++j) {
                    float4 x0 = *(const float4*)(qrow + j * 8);
                    float4 x1 = *(const float4*)(qrow + j * 8 + 4);
                    float4 m0 = *(const float4*)(mrow + j * 8);
                    float4 m1 = *(const float4*)(mrow + j * 8 + 4);
                    uint4 pk;
                    pk.x = (unsigned)bf16rne(x0.x * m0.x) |
                           ((unsigned)bf16rne(x0.y * m0.y) << 16);
                    pk.y = (unsigned)bf16rne(x0.z * m0.z) |
                           ((unsigned)bf16rne(x0.w * m0.w) << 16);
                    pk.z = (unsigned)bf16rne(x1.x * m1.x) |
                           ((unsigned)bf16rne(x1.y * m1.y) << 16);
                    pk.w = (unsigned)bf16rne(x1.z * m1.z) |
                           ((unsigned)bf16rne(x1.w * m1.w) << 16);
                    int slot = (akb >> 3) + j;
                    A4[ar * 8 + (slot ^ (ar & 7))] = pk;
                }
            }
            __syncthreads();
            // MFMA: 2 k-halves x 16 frag-products
            #pragma unroll
            for (int kk = 0; kk < 2; ++kk) {
                bf16x8 af[4], bf[4];
                #pragma unroll
                for (int f = 0; f < 4; ++f) {
                    int rowa = wr * 64 + f * 16 + l15;
                    int slot = kk * 4 + l4;
                    af[f] = __builtin_bit_cast(bf16x8,
                              A4[rowa * 8 + (slot ^ (rowa & 7))]);
                    int rowb = wc * 64 + f * 16 + l15;
                    bf[f] = __builtin_bit_cast(bf16x8,
                              B4[rowb * 8 + (slot ^ (rowb & 7))]);
                }
                #pragma unroll
                for (int i = 0; i < 4; ++i)
                    #pragma unroll
                    for (int j = 0; j < 4; ++j)
                        acc[i][j] = __builtin_amdgcn_mfma_f32_16x16x32_bf16(
                            af[i], bf[j], acc[i][j], 0, 0, 0);
            }
        }
        // epilogue: two half-tile phases through SIM LDS
        __syncthreads();
        if (wr == 0) {
            #pragma unroll
            for (int i = 0; i < 4; ++i)
                #pragma unroll
                for (int j = 0; j < 4; ++j)
                    #pragma unroll
                    for (int rg = 0; rg < 4; ++rg)
                        SIM[(i * 16 + l4 * 4 + rg) * 129 + wc * 64 + j * 16 + l15] =
                            acc[i][j][rg];
        }
        __syncthreads();
        if (tid < 64) {
            const float* rp = SIM + tid * 129;
            #pragma unroll 1
            for (int c = 0; c < 128; ++c) {
                float cv = rp[c];
                if (cv > v[NC_Q - 1]) {
                    v[NC_Q - 1] = cv; ix[NC_Q - 1] = col0 + c;
                    #pragma unroll
                    for (int s = NC_Q - 1; s > 0; --s)
                        if (v[s] > v[s - 1]) {
                            float tv = v[s]; v[s] = v[s - 1]; v[s - 1] = tv;
                            int ti = ix[s]; ix[s] = ix[s - 1]; ix[s - 1] = ti;
                        }
                }
            }
        }
        __syncthreads();
        if (wr == 1) {
            #pragma unroll
            for (int i = 0; i < 4; ++i)
                #pragma unroll
                for (int j = 0; j < 4; ++j)
                    #pragma unroll
                    for (int rg = 0; rg < 4; ++rg)
                        SIM[(i * 16 + l4 * 4 + rg) * 129 + wc * 64 + j * 16 + l15] =
                            acc[i][j][rg];
        }
        __syncthreads();
        if (tid >= 64 && tid < 128) {
            const float* rp = SIM + (tid - 64) * 129;
            #pragma unroll 1
            for (int c = 0; c < 128; ++c) {
                float cv = rp[c];
                if (cv > v[NC_Q - 1]) {
                    v[NC_Q - 1] = cv; ix[NC_Q - 1] = col0 + c;
                    #pragma unroll
                    for (int s = NC_Q - 1; s > 0; --s)
                        if (v[s] > v[s - 1]) {
                            float tv = v[s]; v[s] = v[s - 1]; v[s - 1] = tv;
                            int ti = ix[s]; ix[s] = ix[s - 1]; ix[s - 1] = ti;
                        }
                }
            }
        }
    }
    if (tid < 128) {
        int grow = row0 + tid;
        #pragma unroll
        for (int s = 0; s < NC_Q; ++s)
            candi[(size_t)grow * NCAND + qq * NC_Q + s] = ix[s];
    }
}

// ---------------- kernel E: bit-faithful KC=320 rescore (frozen math) -------
__global__ __launch_bounds__(256) void rescore_kernel(
    const float* __restrict__ q, const float* __restrict__ knn,
    const float* __restrict__ mean, const int* __restrict__ candi,
    float* __restrict__ topw, int* __restrict__ topi) {
    __shared__ float anbuf[4][D_DIM];
    __shared__ float vbuf[4][NCAND];
    __shared__ int ibuf[4][NCAND];
    int wave = threadIdx.x >> 6, lane = threadIdx.x & 63;
    int b = blockIdx.x * 4 + wave;
    const float* qr = q + (size_t)b * D_DIM;

    float nqd;
    if (lane == 0) {
        float nq = np_norm1024_sq(qr, mean, 1);
        nqd = fmaxf(__fsqrt_rn(nq), EPSV);
    }
    nqd = __shfl(nqd, 0);

    #pragma unroll
    for (int rep = 0; rep < 16; ++rep) {
        int d = rep * 64 + lane;
        float a = __fmul_rn(qr[d], mean[d]);
        anbuf[wave][d] = __fdiv_rn(a, nqd);
    }
    __syncthreads();

    // each lane: one candidate, KC=320 chunked sequential FMA chains
    {
        int id = candi[(size_t)b * NCAND + lane];
        const float* kr = knn + (size_t)id * D_DIM;
        const float* an = anbuf[wave];
        float c1 = 0.f, c2 = 0.f, c3 = 0.f, c4 = 0.f;
        #pragma unroll 8
        for (int d = 0; d < 320; ++d)
            c1 = __fmaf_rn(an[d], kr[d], c1);
        #pragma unroll 8
        for (int d = 320; d < 640; ++d)
            c2 = __fmaf_rn(an[d], kr[d], c2);
        #pragma unroll 8
        for (int d = 640; d < 960; ++d)
            c3 = __fmaf_rn(an[d], kr[d], c3);
        #pragma unroll 8
        for (int d = 960; d < 1024; ++d)
            c4 = __fmaf_rn(an[d], kr[d], c4);
        vbuf[wave][lane] = __fadd_rn(__fadd_rn(__fadd_rn(c1, c2), c3), c4);
        ibuf[wave][lane] = id;
    }
    __syncthreads();

    if (lane == 0) {
        float sv[TOPK]; int si[TOPK];
        unsigned long long used = 0ull;
        #pragma unroll 1
        for (int s = 0; s < TOPK; ++s) {
            float bv = -1e30f; int bid = 0x7fffffff; int bc = 0;
            #pragma unroll 1
            for (int c = 0; c < NCAND; ++c) {
                if (used & (1ull << c)) continue;
                float cv = vbuf[wave][c];
                int cid = ibuf[wave][c];
                if (cv > bv || (cv == bv && cid < bid)) {
                    bv = cv; bid = cid; bc = c;
                }
            }
            used |= (1ull << bc);
            sv[s] = bv; si[s] = bid;
        }
        float m = sv[0];
        float w[TOPK];
        float ssum = 0.f;
        #pragma unroll
        for (int k = 0; k < TOPK; ++k) { w[k] = expf(sv[k] - m); ssum += w[k]; }
        float rs = 1.0f / ssum;
        #pragma unroll
        for (int k = 0; k < TOPK; ++k) {
            topw[b * TOPK + k] = w[k] * rs;
            topi[b * TOPK + k] = si[k];
        }
    }
}

// ---------------- kernel F: weighted gather + outputs (frozen) --------------
__global__ void output_kernel(const float* __restrict__ topw,
                              const int* __restrict__ topi,
                              const float* __restrict__ prompts,
                              const float* __restrict__ keys,
                              float* __restrict__ out) {
    int b = blockIdx.x;
    float w[TOPK];
    int id[TOPK];
    #pragma unroll
    for (int k = 0; k < TOPK; ++k) {
        w[k] = topw[b * TOPK + k];
        id[k] = topi[b * TOPK + k];
    }

    const size_t OFF1 = (size_t)B_ROWS * D_DIM;
    const size_t OFF2 = OFF1 + (size_t)B_ROWS * TOPK;

    if (threadIdx.x < TOPK)
        out[OFF1 + (size_t)b * TOPK + threadIdx.x] = (float)id[threadIdx.x];

    int d0 = threadIdx.x * 4;
    float4 acc; acc.x = acc.y = acc.z = acc.w = 0.f;
    #pragma unroll
    for (int k = 0; k < TOPK; ++k) {
        const float* pr = prompts + (size_t)id[k] * D_DIM + d0;
        float4 pv = *(const float4*)pr;
        acc.x += w[k] * pv.x; acc.y += w[k] * pv.y;
        acc.z += w[k] * pv.z; acc.w += w[k] * pv.w;
        const float* kr = keys + (size_t)id[k] * D_DIM + d0;
        float4 kv = *(const float4*)kr;
        *(float4*)(out + OFF2 + ((size_t)b * TOPK + k) * D_DIM + d0) = kv;
    }
    *(float4*)(out + (size_t)b * D_DIM + d0) = acc;
}

// ---------------- launch ----------------
extern "C" void kernel_launch(void* const* d_in, const int* in_sizes, int n_in,
                              void* d_out, int out_size, void* d_ws, size_t ws_size,
                              hipStream_t stream) {
    const float* query   = (const float*)d_in[0];
    const float* prompts = (const float*)d_in[1];
    const float* keys    = (const float*)d_in[2];
    const float* attn    = (const float*)d_in[3];
    float* ws = (float*)d_ws;
    float* out = (float*)d_out;

    float* mean  = ws + WS_MEAN;
    float* knorm = ws + WS_KNORM;
    float* knn   = ws + WS_KNN;
    unsigned short* kn16 = (unsigned short*)(ws + WS_KN16);
    int*   candi = (int*)(ws + WS_CI);
    float* topw  = ws + WS_TW;
    int*   topi  = (int*)(ws + WS_TI);

    seqmean_kernel<<<4, 256, 0, stream>>>(attn, mean);
    knorm_kernel<<<(N_COMP + 255) / 256, 256, 0, stream>>>(keys, knorm);
    knn_kernel<<<N_COMP, 256, 0, stream>>>(keys, knorm, knn, kn16);
    simtop_mfma<<<512, 256, 0, stream>>>(query, mean, kn16, candi);
    rescore_kernel<<<B_ROWS / 4, 256, 0, stream>>>(query, knn, mean, candi,
                                                   topw, topi);
    output_kernel<<<B_ROWS, 256, 0, stream>>>(topw, topi, prompts, keys, out);
}

// Round 9
// 2046.967 us; speedup vs baseline: 3.9592x; 2.3483x over previous
//
#include <hip/hip_runtime.h>
#include <math.h>

#define D_DIM 1024
#define N_COMP 4096
#define B_ROWS 16384
#define TOPK 8
#define NC_Q 16
#define NCAND 64
#define EPSV 1e-8f

typedef __bf16 bf16x8 __attribute__((ext_vector_type(8)));
typedef float f32x4 __attribute__((ext_vector_type(4)));

// ---------------- workspace layout (in float slots) ----------------
#define WS_MEAN  0         // 1024
#define WS_KNORM 1024      // 4096
#define WS_KNN   5120      // 4096*1024 f32 (bit-exact k_n, rescore input)
#define WS_KN16  4199424   // 4096*1024 bf16 (ushort) = 2097152 float slots
#define WS_CI    6296576   // candidate idx: 16384*64 ints
#define WS_TW    7345152   // softmax weights: 16384*8
#define WS_TI    7476224   // final idx: 16384*8 ints
// total 7607296 floats = 30.4 MB

__device__ __forceinline__ unsigned short bf16rne(float f) {
    unsigned int u = __float_as_uint(f);
    return (unsigned short)((u + 0x7FFFu + ((u >> 16) & 1u)) >> 16);
}

__device__ __forceinline__ void gload16(const void* g, void* l) {
    __builtin_amdgcn_global_load_lds(
        (const __attribute__((address_space(1))) void*)g,
        (__attribute__((address_space(3))) void*)l, 16, 0, 0);
}

// ===== numpy npyv pairwise-sum emulation (PASSED in R7 — frozen) =====
__device__ __forceinline__ float np_leaf128(const float* __restrict__ x,
                                            const float* __restrict__ m,
                                            int mode) {
    float lane[16];
    #pragma unroll
    for (int l = 0; l < 16; ++l) {
        float p[8];
        #pragma unroll
        for (int j = 0; j < 8; ++j) {
            float e = x[16 * j + l];
            if (mode == 1) e = __fmul_rn(e, m[16 * j + l]);
            p[j] = __fmul_rn(e, e);
        }
        float t0 = __fadd_rn(p[0], p[1]);
        float t1 = __fadd_rn(p[2], p[3]);
        float t2 = __fadd_rn(p[4], p[5]);
        float t3 = __fadd_rn(p[6], p[7]);
        lane[l] = __fadd_rn(__fadd_rn(t0, t1), __fadd_rn(t2, t3));
    }
    float a[8], b[4], c[2];
    #pragma unroll
    for (int l = 0; l < 8; ++l) a[l] = __fadd_rn(lane[l], lane[l + 8]);
    #pragma unroll
    for (int l = 0; l < 4; ++l) b[l] = __fadd_rn(a[l], a[l + 4]);
    #pragma unroll
    for (int l = 0; l < 2; ++l) c[l] = __fadd_rn(b[l], b[l + 2]);
    return __fadd_rn(c[0], c[1]);
}

__device__ __forceinline__ float np_norm1024_sq(const float* __restrict__ x,
                                                const float* __restrict__ m,
                                                int mode) {
    float L[8];
    #pragma unroll
    for (int ch = 0; ch < 8; ++ch)
        L[ch] = np_leaf128(x + ch * 128, m ? m + ch * 128 : m, mode);
    return __fadd_rn(
        __fadd_rn(__fadd_rn(L[0], L[1]), __fadd_rn(L[2], L[3])),
        __fadd_rn(__fadd_rn(L[4], L[5]), __fadd_rn(L[6], L[7])));
}

// ---------------- kernel A: np-faithful mean (frozen bits) ------------------
__global__ void seqmean_kernel(const float* __restrict__ attn,
                               float* __restrict__ mean) {
    int d = blockIdx.x * 256 + threadIdx.x;
    float s = 0.f;
    #pragma unroll 16
    for (int n = 0; n < N_COMP; ++n)
        s = __fadd_rn(s, attn[(size_t)n * D_DIM + d]);
    mean[d] = __fdiv_rn(s, (float)N_COMP);
}

// ---------------- kernel B: np-faithful key norms (frozen) ------------------
__global__ void knorm_kernel(const float* __restrict__ keys,
                             float* __restrict__ knorm) {
    int n = blockIdx.x * 256 + threadIdx.x;
    if (n >= N_COMP) return;
    float nk = np_norm1024_sq(keys + (size_t)n * D_DIM, nullptr, 0);
    knorm[n] = fmaxf(__fsqrt_rn(nk), EPSV);
}

// ---------------- kernel C: knn f32 (frozen bits) + bf16 copy ---------------
__global__ void knn_kernel(const float* __restrict__ keys,
                           const float* __restrict__ knorm,
                           float* __restrict__ knn,
                           unsigned short* __restrict__ kn16) {
    int n = blockIdx.x;
    float kn = knorm[n];
    int d = threadIdx.x * 4;
    const float* row = keys + (size_t)n * D_DIM + d;
    float* orow = knn + (size_t)n * D_DIM + d;
    unsigned short* o16 = kn16 + (size_t)n * D_DIM + d;
    float r0 = __fdiv_rn(row[0], kn);
    float r1 = __fdiv_rn(row[1], kn);
    float r2 = __fdiv_rn(row[2], kn);
    float r3 = __fdiv_rn(row[3], kn);
    orow[0] = r0; orow[1] = r1; orow[2] = r2; orow[3] = r3;
    o16[0] = bf16rne(r0); o16[1] = bf16rne(r1);
    o16[2] = bf16rne(r2); o16[3] = bf16rne(r3);
}

// ---------------- kernel D: MFMA bf16 GEMM + per-quarter top-16 (as R8) -----
__global__ __launch_bounds__(256, 2) void simtop_mfma(
    const float* __restrict__ qf, const float* __restrict__ mean,
    const unsigned short* __restrict__ kn16, int* __restrict__ candi) {
    __shared__ __align__(16) char RAW[65536];
    uint4* A4 = (uint4*)RAW;               // [128 rows][8 slots]
    uint4* B4 = (uint4*)(RAW + 16384);     // [128 cols][8 slots]
    float* SIM = (float*)(RAW + 31744);    // [64][129], overlays B4 tail (dead)

    const int tid = threadIdx.x;
    const int lane = tid & 63;
    const int wid = tid >> 6;
    const int wr = wid >> 1, wc = wid & 1;
    const int l15 = lane & 15, l4 = lane >> 4;
    const int rb = blockIdx.x >> 2;
    const int qq = blockIdx.x & 3;
    const int row0 = rb * 128;
    const int colQ = qq * 1024;

    float v[NC_Q]; int ix[NC_Q];
    #pragma unroll
    for (int s = 0; s < NC_Q; ++s) { v[s] = -1e30f; ix[s] = 0; }

    const int br = tid >> 3, bj = tid & 7;
    const int ar = tid >> 1, akb = (tid & 1) * 32;

    for (int ct = 0; ct < 8; ++ct) {
        const int col0 = colQ + ct * 128;
        f32x4 acc[4][4];
        #pragma unroll
        for (int i = 0; i < 4; ++i)
            #pragma unroll
            for (int j = 0; j < 4; ++j) {
                acc[i][j][0] = 0.f; acc[i][j][1] = 0.f;
                acc[i][j][2] = 0.f; acc[i][j][3] = 0.f;
            }

        for (int kt = 0; kt < 16; ++kt) {
            const int k0 = kt * 64;
            __syncthreads();
            #pragma unroll
            for (int c = 0; c < 4; ++c) {
                int r = c * 32 + br;
                int jg = bj ^ (r & 7);
                gload16(kn16 + (size_t)(col0 + r) * D_DIM + k0 + jg * 8,
                        (char*)B4 + c * 4096 + tid * 16);
            }
            {
                const float* qrow = qf + (size_t)(row0 + ar) * D_DIM + k0 + akb;
                const float* mrow = mean + k0 + akb;
                #pragma unroll
                for (int j = 0; j < 4; ++j) {
                    float4 x0 = *(const float4*)(qrow + j * 8);
                    float4 x1 = *(const float4*)(qrow + j * 8 + 4);
                    float4 m0 = *(const float4*)(mrow + j * 8);
                    float4 m1 = *(const float4*)(mrow + j * 8 + 4);
                    uint4 pk;
                    pk.x = (unsigned)bf16rne(x0.x * m0.x) |
                           ((unsigned)bf16rne(x0.y * m0.y) << 16);
                    pk.y = (unsigned)bf16rne(x0.z * m0.z) |
                           ((unsigned)bf16rne(x0.w * m0.w) << 16);
                    pk.z = (unsigned)bf16rne(x1.x * m1.x) |
                           ((unsigned)bf16rne(x1.y * m1.y) << 16);
                    pk.w = (unsigned)bf16rne(x1.z * m1.z) |
                           ((unsigned)bf16rne(x1.w * m1.w) << 16);
                    int slot = (akb >> 3) + j;
                    A4[ar * 8 + (slot ^ (ar & 7))] = pk;
                }
            }
            __syncthreads();
            #pragma unroll
            for (int kk = 0; kk < 2; ++kk) {
                bf16x8 af[4], bf[4];
                #pragma unroll
                for (int f = 0; f < 4; ++f) {
                    int rowa = wr * 64 + f * 16 + l15;
                    int slot = kk * 4 + l4;
                    af[f] = __builtin_bit_cast(bf16x8,
                              A4[rowa * 8 + (slot ^ (rowa & 7))]);
                    int rowb = wc * 64 + f * 16 + l15;
                    bf[f] = __builtin_bit_cast(bf16x8,
                              B4[rowb * 8 + (slot ^ (rowb & 7))]);
                }
                #pragma unroll
                for (int i = 0; i < 4; ++i)
                    #pragma unroll
                    for (int j = 0; j < 4; ++j)
                        acc[i][j] = __builtin_amdgcn_mfma_f32_16x16x32_bf16(
                            af[i], bf[j], acc[i][j], 0, 0, 0);
            }
        }
        __syncthreads();
        if (wr == 0) {
            #pragma unroll
            for (int i = 0; i < 4; ++i)
                #pragma unroll
                for (int j = 0; j < 4; ++j)
                    #pragma unroll
                    for (int rg = 0; rg < 4; ++rg)
                        SIM[(i * 16 + l4 * 4 + rg) * 129 + wc * 64 + j * 16 + l15] =
                            acc[i][j][rg];
        }
        __syncthreads();
        if (tid < 64) {
            const float* rp = SIM + tid * 129;
            #pragma unroll 1
            for (int c = 0; c < 128; ++c) {
                float cv = rp[c];
                if (cv > v[NC_Q - 1]) {
                    v[NC_Q - 1] = cv; ix[NC_Q - 1] = col0 + c;
                    #pragma unroll
                    for (int s = NC_Q - 1; s > 0; --s)
                        if (v[s] > v[s - 1]) {
                            float tv = v[s]; v[s] = v[s - 1]; v[s - 1] = tv;
                            int ti = ix[s]; ix[s] = ix[s - 1]; ix[s - 1] = ti;
                        }
                }
            }
        }
        __syncthreads();
        if (wr == 1) {
            #pragma unroll
            for (int i = 0; i < 4; ++i)
                #pragma unroll
                for (int j = 0; j < 4; ++j)
                    #pragma unroll
                    for (int rg = 0; rg < 4; ++rg)
                        SIM[(i * 16 + l4 * 4 + rg) * 129 + wc * 64 + j * 16 + l15] =
                            acc[i][j][rg];
        }
        __syncthreads();
        if (tid >= 64 && tid < 128) {
            const float* rp = SIM + (tid - 64) * 129;
            #pragma unroll 1
            for (int c = 0; c < 128; ++c) {
                float cv = rp[c];
                if (cv > v[NC_Q - 1]) {
                    v[NC_Q - 1] = cv; ix[NC_Q - 1] = col0 + c;
                    #pragma unroll
                    for (int s = NC_Q - 1; s > 0; --s)
                        if (v[s] > v[s - 1]) {
                            float tv = v[s]; v[s] = v[s - 1]; v[s - 1] = tv;
                            int ti = ix[s]; ix[s] = ix[s - 1]; ix[s - 1] = ti;
                        }
                }
            }
        }
    }
    if (tid < 128) {
        int grow = row0 + tid;
        #pragma unroll
        for (int s = 0; s < NC_Q; ++s)
            candi[(size_t)grow * NCAND + qq * NC_Q + s] = ix[s];
    }
}

// ---------------- kernel E: bit-faithful KC=320 rescore, parallelized -------
// One block per query row. tid = cand*4 + chunk. Bit-identical float ops to
// the R7 PASSED version; only the lane assignment changed.
__global__ __launch_bounds__(256) void rescore_kernel(
    const float* __restrict__ q, const float* __restrict__ knn,
    const float* __restrict__ mean, const int* __restrict__ candi,
    float* __restrict__ topw, int* __restrict__ topi) {
    __shared__ float anbuf[D_DIM];
    __shared__ float vbuf[NCAND];
    __shared__ int ibuf[NCAND];
    __shared__ float snq;
    const int tid = threadIdx.x;
    const int wave = tid >> 6, lane = tid & 63;
    const int b = blockIdx.x;
    const float* qr = q + (size_t)b * D_DIM;

    // ---- wave 0: numpy pairwise norm tree, lane-parallel, bit-exact ----
    if (wave == 0) {
        const int l = lane & 15, g = lane >> 4;
        float lv0, lv1;
        {
            const float* x = qr + g * 128;
            const float* m = mean + g * 128;
            float p[8];
            #pragma unroll
            for (int j = 0; j < 8; ++j) {
                float e = __fmul_rn(x[16 * j + l], m[16 * j + l]);
                p[j] = __fmul_rn(e, e);
            }
            float t0 = __fadd_rn(p[0], p[1]);
            float t1 = __fadd_rn(p[2], p[3]);
            float t2 = __fadd_rn(p[4], p[5]);
            float t3 = __fadd_rn(p[6], p[7]);
            lv0 = __fadd_rn(__fadd_rn(t0, t1), __fadd_rn(t2, t3));
        }
        {
            const float* x = qr + (g + 4) * 128;
            const float* m = mean + (g + 4) * 128;
            float p[8];
            #pragma unroll
            for (int j = 0; j < 8; ++j) {
                float e = __fmul_rn(x[16 * j + l], m[16 * j + l]);
                p[j] = __fmul_rn(e, e);
            }
            float t0 = __fadd_rn(p[0], p[1]);
            float t1 = __fadd_rn(p[2], p[3]);
            float t2 = __fadd_rn(p[4], p[5]);
            float t3 = __fadd_rn(p[6], p[7]);
            lv1 = __fadd_rn(__fadd_rn(t0, t1), __fadd_rn(t2, t3));
        }
        // fold-by-halves (numpy _mm512_reduce_add_ps order)
        #pragma unroll
        for (int off = 8; off >= 1; off >>= 1) {
            lv0 = __fadd_rn(lv0, __shfl_down(lv0, off));
            lv1 = __fadd_rn(lv1, __shfl_down(lv1, off));
        }
        float L0 = __shfl(lv0, 0),  L1 = __shfl(lv0, 16),
              L2 = __shfl(lv0, 32), L3 = __shfl(lv0, 48);
        float L4 = __shfl(lv1, 0),  L5 = __shfl(lv1, 16),
              L6 = __shfl(lv1, 32), L7 = __shfl(lv1, 48);
        if (lane == 0) {
            float nq = __fadd_rn(
                __fadd_rn(__fadd_rn(L0, L1), __fadd_rn(L2, L3)),
                __fadd_rn(__fadd_rn(L4, L5), __fadd_rn(L6, L7)));
            snq = fmaxf(__fsqrt_rn(nq), EPSV);
        }
    }
    __syncthreads();
    const float nqd = snq;

    // ---- all threads: materialize f32 aq_n (bitwise = numpy) ----
    {
        int d0 = tid * 4;
        float4 qv = *(const float4*)(qr + d0);
        float4 mv = *(const float4*)(mean + d0);
        anbuf[d0 + 0] = __fdiv_rn(__fmul_rn(qv.x, mv.x), nqd);
        anbuf[d0 + 1] = __fdiv_rn(__fmul_rn(qv.y, mv.y), nqd);
        anbuf[d0 + 2] = __fdiv_rn(__fmul_rn(qv.z, mv.z), nqd);
        anbuf[d0 + 3] = __fdiv_rn(__fmul_rn(qv.w, mv.w), nqd);
    }
    __syncthreads();

    // ---- chunk-parallel KC=320 chains: tid = cand*4 + chunk ----
    {
        const int c = tid >> 2, chunk = tid & 3;
        const int id = candi[(size_t)b * NCAND + c];
        const int start = chunk * 320;
        const int n4 = (chunk == 3) ? 16 : 80;   // floats/4
        const float4* k4 = (const float4*)(knn + (size_t)id * D_DIM + start);
        const float4* a4 = (const float4*)(anbuf + start);
        float acc = 0.f;
        #pragma unroll 4
        for (int t = 0; t < n4; ++t) {
            float4 kv = k4[t];
            float4 av = a4[t];
            acc = __fmaf_rn(av.x, kv.x, acc);
            acc = __fmaf_rn(av.y, kv.y, acc);
            acc = __fmaf_rn(av.z, kv.z, acc);
            acc = __fmaf_rn(av.w, kv.w, acc);
        }
        // combine ((c1+c2)+c3)+c4 on chunk-0 lane (exact OpenBLAS order)
        float c2 = __shfl_down(acc, 1);
        float c3 = __shfl_down(acc, 2);
        float c4 = __shfl_down(acc, 3);
        if (chunk == 0) {
            vbuf[c] = __fadd_rn(__fadd_rn(__fadd_rn(acc, c2), c3), c4);
            ibuf[c] = id;
        }
    }
    __syncthreads();

    // ---- wave 0: butterfly top-8 knockout (val desc, idx asc) ----
    if (wave == 0) {
        float v = vbuf[lane];
        int id = ibuf[lane];
        float sv[TOPK]; int si[TOPK];
        #pragma unroll
        for (int s = 0; s < TOPK; ++s) {
            float bv = v; int bid = id;
            #pragma unroll
            for (int off = 32; off >= 1; off >>= 1) {
                float ov = __shfl_xor(bv, off);
                int oid = __shfl_xor(bid, off);
                if (ov > bv || (ov == bv && oid < bid)) { bv = ov; bid = oid; }
            }
            sv[s] = bv; si[s] = bid;
            if (id == bid) v = -1e30f;
        }
        if (lane == 0) {
            float m = sv[0];
            float w[TOPK];
            float ssum = 0.f;
            #pragma unroll
            for (int k = 0; k < TOPK; ++k) { w[k] = expf(sv[k] - m); ssum += w[k]; }
            float rs = 1.0f / ssum;
            #pragma unroll
            for (int k = 0; k < TOPK; ++k) {
                topw[b * TOPK + k] = w[k] * rs;
                topi[b * TOPK + k] = si[k];
            }
        }
    }
}

// ---------------- kernel F: weighted gather + outputs (frozen) --------------
__global__ void output_kernel(const float* __restrict__ topw,
                              const int* __restrict__ topi,
                              const float* __restrict__ prompts,
                              const float* __restrict__ keys,
                              float* __restrict__ out) {
    int b = blockIdx.x;
    float w[TOPK];
    int id[TOPK];
    #pragma unroll
    for (int k = 0; k < TOPK; ++k) {
        w[k] = topw[b * TOPK + k];
        id[k] = topi[b * TOPK + k];
    }

    const size_t OFF1 = (size_t)B_ROWS * D_DIM;
    const size_t OFF2 = OFF1 + (size_t)B_ROWS * TOPK;

    if (threadIdx.x < TOPK)
        out[OFF1 + (size_t)b * TOPK + threadIdx.x] = (float)id[threadIdx.x];

    int d0 = threadIdx.x * 4;
    float4 acc; acc.x = acc.y = acc.z = acc.w = 0.f;
    #pragma unroll
    for (int k = 0; k < TOPK; ++k) {
        const float* pr = prompts + (size_t)id[k] * D_DIM + d0;
        float4 pv = *(const float4*)pr;
        acc.x += w[k] * pv.x; acc.y += w[k] * pv.y;
        acc.z += w[k] * pv.z; acc.w += w[k] * pv.w;
        const float* kr = keys + (size_t)id[k] * D_DIM + d0;
        float4 kv = *(const float4*)kr;
        *(float4*)(out + OFF2 + ((size_t)b * TOPK + k) * D_DIM + d0) = kv;
    }
    *(float4*)(out + (size_t)b * D_DIM + d0) = acc;
}

// ---------------- launch ----------------
extern "C" void kernel_launch(void* const* d_in, const int* in_sizes, int n_in,
                              void* d_out, int out_size, void* d_ws, size_t ws_size,
                              hipStream_t stream) {
    const float* query   = (const float*)d_in[0];
    const float* prompts = (const float*)d_in[1];
    const float* keys    = (const float*)d_in[2];
    const float* attn    = (const float*)d_in[3];
    float* ws = (float*)d_ws;
    float* out = (float*)d_out;

    float* mean  = ws + WS_MEAN;
    float* knorm = ws + WS_KNORM;
    float* knn   = ws + WS_KNN;
    unsigned short* kn16 = (unsigned short*)(ws + WS_KN16);
    int*   candi = (int*)(ws + WS_CI);
    float* topw  = ws + WS_TW;
    int*   topi  = (int*)(ws + WS_TI);

    seqmean_kernel<<<4, 256, 0, stream>>>(attn, mean);
    knorm_kernel<<<(N_COMP + 255) / 256, 256, 0, stream>>>(keys, knorm);
    knn_kernel<<<N_COMP, 256, 0, stream>>>(keys, knorm, knn, kn16);
    simtop_mfma<<<512, 256, 0, stream>>>(query, mean, kn16, candi);
    rescore_kernel<<<B_ROWS, 256, 0, stream>>>(query, knn, mean, candi,
                                               topw, topi);
    output_kernel<<<B_ROWS, 256, 0, stream>>>(topw, topi, prompts, keys, out);
}

// Round 10
// 1356.947 us; speedup vs baseline: 5.9724x; 1.5085x over previous
//
#include <hip/hip_runtime.h>
#include <math.h>

#define D_DIM 1024
#define N_COMP 4096
#define B_ROWS 16384
#define TOPK 8
#define NC_Q 16
#define NCAND 64
#define EPSV 1e-8f

typedef __bf16 bf16x8 __attribute__((ext_vector_type(8)));
typedef float f32x4 __attribute__((ext_vector_type(4)));

// ---------------- workspace layout (in float slots) ----------------
#define WS_MEAN  0         // 1024
#define WS_KNORM 1024      // 4096
#define WS_KNN   5120      // 4096*1024 f32 (bit-exact k_n, rescore input)
#define WS_KN16  4199424   // 4096*1024 bf16 (ushort) = 2097152 float slots
#define WS_CI    6296576   // candidate idx: 16384*64 ints
#define WS_TW    7345152   // softmax weights: 16384*8
#define WS_TI    7476224   // final idx: 16384*8 ints

__device__ __forceinline__ unsigned short bf16rne(float f) {
    unsigned int u = __float_as_uint(f);
    return (unsigned short)((u + 0x7FFFu + ((u >> 16) & 1u)) >> 16);
}

__device__ __forceinline__ void gload16(const void* g, void* l) {
    __builtin_amdgcn_global_load_lds(
        (const __attribute__((address_space(1))) void*)g,
        (__attribute__((address_space(3))) void*)l, 16, 0, 0);
}

// ---------------- kernel A: np-faithful mean via LDS transpose --------------
// Bit-exact: per column d, s = fadd chain over n = 0..4095 ascending.
__global__ void seqmean_kernel(const float* __restrict__ attn,
                               float* __restrict__ mean) {
    __shared__ float tile[128][65];
    const int tid = threadIdx.x;
    const int d0 = blockIdx.x * 64;
    const int c = tid & 63, r0 = tid >> 6;
    float acc = 0.f;
    for (int chunk = 0; chunk < 32; ++chunk) {
        const int base = chunk * 128;
        __syncthreads();
        #pragma unroll
        for (int rr = 0; rr < 32; ++rr) {
            int r = r0 * 32 + rr;
            tile[r][c] = attn[(size_t)(base + r) * D_DIM + d0 + c];
        }
        __syncthreads();
        if (tid < 64) {
            #pragma unroll 8
            for (int r = 0; r < 128; ++r)
                acc = __fadd_rn(acc, tile[r][tid]);
        }
    }
    if (tid < 64) mean[d0 + tid] = __fdiv_rn(acc, (float)N_COMP);
}

// ---------------- kernel B: np-faithful key norms, lane-parallel tree -------
// Exact emulation of numpy npyv pairwise (16-lane leaves, fold-by-halves).
__global__ void knorm_kernel(const float* __restrict__ keys,
                             float* __restrict__ knorm) {
    const int wave = threadIdx.x >> 6, lane = threadIdx.x & 63;
    const int n = blockIdx.x * 4 + wave;
    const float* x = keys + (size_t)n * D_DIM;
    const int l = lane & 15, g = lane >> 4;
    float lv0, lv1;
    {
        const float* xx = x + g * 128;
        float p[8];
        #pragma unroll
        for (int j = 0; j < 8; ++j) {
            float e = xx[16 * j + l];
            p[j] = __fmul_rn(e, e);
        }
        float t0 = __fadd_rn(p[0], p[1]), t1 = __fadd_rn(p[2], p[3]);
        float t2 = __fadd_rn(p[4], p[5]), t3 = __fadd_rn(p[6], p[7]);
        lv0 = __fadd_rn(__fadd_rn(t0, t1), __fadd_rn(t2, t3));
    }
    {
        const float* xx = x + (g + 4) * 128;
        float p[8];
        #pragma unroll
        for (int j = 0; j < 8; ++j) {
            float e = xx[16 * j + l];
            p[j] = __fmul_rn(e, e);
        }
        float t0 = __fadd_rn(p[0], p[1]), t1 = __fadd_rn(p[2], p[3]);
        float t2 = __fadd_rn(p[4], p[5]), t3 = __fadd_rn(p[6], p[7]);
        lv1 = __fadd_rn(__fadd_rn(t0, t1), __fadd_rn(t2, t3));
    }
    #pragma unroll
    for (int off = 8; off >= 1; off >>= 1) {
        lv0 = __fadd_rn(lv0, __shfl_down(lv0, off));
        lv1 = __fadd_rn(lv1, __shfl_down(lv1, off));
    }
    float L0 = __shfl(lv0, 0),  L1 = __shfl(lv0, 16),
          L2 = __shfl(lv0, 32), L3 = __shfl(lv0, 48);
    float L4 = __shfl(lv1, 0),  L5 = __shfl(lv1, 16),
          L6 = __shfl(lv1, 32), L7 = __shfl(lv1, 48);
    if (lane == 0) {
        float nk = __fadd_rn(
            __fadd_rn(__fadd_rn(L0, L1), __fadd_rn(L2, L3)),
            __fadd_rn(__fadd_rn(L4, L5), __fadd_rn(L6, L7)));
        knorm[n] = fmaxf(__fsqrt_rn(nk), EPSV);
    }
}

// ---------------- kernel C: knn f32 (frozen bits) + bf16 copy ---------------
__global__ void knn_kernel(const float* __restrict__ keys,
                           const float* __restrict__ knorm,
                           float* __restrict__ knn,
                           unsigned short* __restrict__ kn16) {
    int n = blockIdx.x;
    float kn = knorm[n];
    int d = threadIdx.x * 4;
    const float* row = keys + (size_t)n * D_DIM + d;
    float* orow = knn + (size_t)n * D_DIM + d;
    unsigned short* o16 = kn16 + (size_t)n * D_DIM + d;
    float r0 = __fdiv_rn(row[0], kn);
    float r1 = __fdiv_rn(row[1], kn);
    float r2 = __fdiv_rn(row[2], kn);
    float r3 = __fdiv_rn(row[3], kn);
    orow[0] = r0; orow[1] = r1; orow[2] = r2; orow[3] = r3;
    o16[0] = bf16rne(r0); o16[1] = bf16rne(r1);
    o16[2] = bf16rne(r2); o16[3] = bf16rne(r3);
}

// ---------------- kernel C2: aq16 = bf16(q * mean), precomputed -------------
__global__ void aq16_kernel(const float* __restrict__ q,
                            const float* __restrict__ mean,
                            unsigned short* __restrict__ aq16) {
    size_t i = ((size_t)blockIdx.x * 256 + threadIdx.x) * 8;
    int d = (int)(i & (D_DIM - 1));
    float4 a0 = *(const float4*)(q + i);
    float4 a1 = *(const float4*)(q + i + 4);
    float4 m0 = *(const float4*)(mean + d);
    float4 m1 = *(const float4*)(mean + d + 4);
    uint4 pk;
    pk.x = (unsigned)bf16rne(a0.x * m0.x) | ((unsigned)bf16rne(a0.y * m0.y) << 16);
    pk.y = (unsigned)bf16rne(a0.z * m0.z) | ((unsigned)bf16rne(a0.w * m0.w) << 16);
    pk.z = (unsigned)bf16rne(a1.x * m1.x) | ((unsigned)bf16rne(a1.y * m1.y) << 16);
    pk.w = (unsigned)bf16rne(a1.z * m1.z) | ((unsigned)bf16rne(a1.w * m1.w) << 16);
    *(uint4*)(aq16 + i) = pk;
}

// ---------------- kernel D: MFMA bf16 GEMM + per-quarter top-16 v2 ----------
// grid = 128 rb x 4 qq (qq = bid&3 -> XCD-affine). Block: 128 rows x 1024
// cols in 4 col-tiles of 256. 8 waves (2 wr x 4 wc). BK=64, 16x16x32 MFMA.
// A (aq16) and B (kn16) both via global_load_lds w=16, XOR-swizzled source.
// SIM scan buffer overlays the staging LDS (dead at epilogue).
__global__ __launch_bounds__(512, 4) void simtop_mfma(
    const unsigned short* __restrict__ aq16,
    const unsigned short* __restrict__ kn16,
    int* __restrict__ candi) {
    __shared__ __align__(16) char RAW[49152];
    uint4* A4 = (uint4*)RAW;               // [128 rows][8 slots] 16KB
    uint4* B4 = (uint4*)(RAW + 16384);     // [256 cols][8 slots] 32KB
    float* SIM = (float*)RAW;              // [64][129] overlay (epilogue)
    float* VM  = (float*)RAW;              // [256][16] overlay (merge)
    int*   IM  = (int*)(RAW + 16384);      // [256][16]

    const int tid = threadIdx.x;
    const int lane = tid & 63;
    const int wid = tid >> 6;
    const int wr = wid >> 2, wc = wid & 3;
    const int l15 = lane & 15, l4 = lane >> 4;
    const int rb = blockIdx.x >> 2;
    const int qq = blockIdx.x & 3;
    const int row0 = rb * 128;
    const int colQ = qq * 1024;
    const int srow = tid & 127;            // scanner-owned block row (tid<256)
    const int sstripe = (tid >> 7) & 1;

    float v[NC_Q]; int ix[NC_Q];
    #pragma unroll
    for (int s = 0; s < NC_Q; ++s) { v[s] = -1e30f; ix[s] = 0; }

    for (int ct = 0; ct < 4; ++ct) {
        const int col0 = colQ + ct * 256;
        f32x4 acc[4][4];
        #pragma unroll
        for (int i = 0; i < 4; ++i)
            #pragma unroll
            for (int j = 0; j < 4; ++j) {
                acc[i][j][0] = 0.f; acc[i][j][1] = 0.f;
                acc[i][j][2] = 0.f; acc[i][j][3] = 0.f;
            }

        for (int kt = 0; kt < 16; ++kt) {
            const int k0 = kt * 64;
            __syncthreads();
            #pragma unroll
            for (int c = 0; c < 2; ++c) {       // A: 128 rows x 8 slots
                int unit = c * 512 + tid;
                int r = unit >> 3, j = unit & 7;
                gload16(aq16 + (size_t)(row0 + r) * D_DIM + k0 + (j ^ (r & 7)) * 8,
                        (char*)A4 + unit * 16);
            }
            #pragma unroll
            for (int c = 0; c < 4; ++c) {       // B: 256 cols x 8 slots
                int unit = c * 512 + tid;
                int r = unit >> 3, j = unit & 7;
                gload16(kn16 + (size_t)(col0 + r) * D_DIM + k0 + (j ^ (r & 7)) * 8,
                        (char*)B4 + unit * 16);
            }
            __syncthreads();
            #pragma unroll
            for (int kk = 0; kk < 2; ++kk) {
                bf16x8 af[4], bfv[4];
                #pragma unroll
                for (int f = 0; f < 4; ++f) {
                    int rowa = wr * 64 + f * 16 + l15;
                    int slot = kk * 4 + l4;
                    af[f] = __builtin_bit_cast(bf16x8,
                              A4[rowa * 8 + (slot ^ (rowa & 7))]);
                    int rowb = wc * 64 + f * 16 + l15;
                    bfv[f] = __builtin_bit_cast(bf16x8,
                              B4[rowb * 8 + (slot ^ (rowb & 7))]);
                }
                #pragma unroll
                for (int i = 0; i < 4; ++i)
                    #pragma unroll
                    for (int j = 0; j < 4; ++j)
                        acc[i][j] = __builtin_amdgcn_mfma_f32_16x16x32_bf16(
                            af[i], bfv[j], acc[i][j], 0, 0, 0);
            }
        }
        // epilogue: 4 phases of (row-half, col-half) through SIM overlay
        #pragma unroll 1
        for (int p = 0; p < 4; ++p) {
            __syncthreads();
            if (wr == (p >> 1) && (wc >> 1) == (p & 1)) {
                #pragma unroll
                for (int i = 0; i < 4; ++i)
                    #pragma unroll
                    for (int j = 0; j < 4; ++j)
                        #pragma unroll
                        for (int rg = 0; rg < 4; ++rg)
                            SIM[(i * 16 + l4 * 4 + rg) * 129 +
                                (wc & 1) * 64 + j * 16 + l15] = acc[i][j][rg];
            }
            __syncthreads();
            if (tid < 256 && (srow >> 6) == (p >> 1)) {
                const float* rp = SIM + (srow & 63) * 129 + sstripe * 64;
                const int gbase = col0 + (p & 1) * 128 + sstripe * 64;
                #pragma unroll 1
                for (int cc = 0; cc < 64; ++cc) {
                    float cv = rp[cc];
                    if (cv > v[NC_Q - 1]) {
                        v[NC_Q - 1] = cv; ix[NC_Q - 1] = gbase + cc;
                        #pragma unroll
                        for (int s = NC_Q - 1; s > 0; --s)
                            if (v[s] > v[s - 1]) {
                                float tv = v[s]; v[s] = v[s - 1]; v[s - 1] = tv;
                                int ti = ix[s]; ix[s] = ix[s - 1]; ix[s - 1] = ti;
                            }
                    }
                }
            }
        }
    }
    __syncthreads();
    if (tid < 256) {
        #pragma unroll
        for (int s = 0; s < NC_Q; ++s) {
            VM[tid * 16 + s] = v[s];
            IM[tid * 16 + s] = ix[s];
        }
    }
    __syncthreads();
    if (tid < 128) {     // merge two sorted stripe lists -> top-16 of the row
        int ia = 0, ib = 0;
        #pragma unroll 1
        for (int s = 0; s < NC_Q; ++s) {
            float va = (ia < 16) ? VM[tid * 16 + ia] : -3e38f;
            float vb = (ib < 16) ? VM[(tid + 128) * 16 + ib] : -3e38f;
            int id;
            if (va >= vb) { id = IM[tid * 16 + ia]; ++ia; }
            else          { id = IM[(tid + 128) * 16 + ib]; ++ib; }
            candi[(size_t)(row0 + tid) * NCAND + qq * 16 + s] = id;
        }
    }
}

// ---------------- kernel E: bit-faithful KC=320 rescore (R9 PASSED, frozen) -
__global__ __launch_bounds__(256) void rescore_kernel(
    const float* __restrict__ q, const float* __restrict__ knn,
    const float* __restrict__ mean, const int* __restrict__ candi,
    float* __restrict__ topw, int* __restrict__ topi) {
    __shared__ float anbuf[D_DIM];
    __shared__ float vbuf[NCAND];
    __shared__ int ibuf[NCAND];
    __shared__ float snq;
    const int tid = threadIdx.x;
    const int wave = tid >> 6, lane = tid & 63;
    const int b = blockIdx.x;
    const float* qr = q + (size_t)b * D_DIM;

    if (wave == 0) {
        const int l = lane & 15, g = lane >> 4;
        float lv0, lv1;
        {
            const float* x = qr + g * 128;
            const float* m = mean + g * 128;
            float p[8];
            #pragma unroll
            for (int j = 0; j < 8; ++j) {
                float e = __fmul_rn(x[16 * j + l], m[16 * j + l]);
                p[j] = __fmul_rn(e, e);
            }
            float t0 = __fadd_rn(p[0], p[1]), t1 = __fadd_rn(p[2], p[3]);
            float t2 = __fadd_rn(p[4], p[5]), t3 = __fadd_rn(p[6], p[7]);
            lv0 = __fadd_rn(__fadd_rn(t0, t1), __fadd_rn(t2, t3));
        }
        {
            const float* x = qr + (g + 4) * 128;
            const float* m = mean + (g + 4) * 128;
            float p[8];
            #pragma unroll
            for (int j = 0; j < 8; ++j) {
                float e = __fmul_rn(x[16 * j + l], m[16 * j + l]);
                p[j] = __fmul_rn(e, e);
            }
            float t0 = __fadd_rn(p[0], p[1]), t1 = __fadd_rn(p[2], p[3]);
            float t2 = __fadd_rn(p[4], p[5]), t3 = __fadd_rn(p[6], p[7]);
            lv1 = __fadd_rn(__fadd_rn(t0, t1), __fadd_rn(t2, t3));
        }
        #pragma unroll
        for (int off = 8; off >= 1; off >>= 1) {
            lv0 = __fadd_rn(lv0, __shfl_down(lv0, off));
            lv1 = __fadd_rn(lv1, __shfl_down(lv1, off));
        }
        float L0 = __shfl(lv0, 0),  L1 = __shfl(lv0, 16),
              L2 = __shfl(lv0, 32), L3 = __shfl(lv0, 48);
        float L4 = __shfl(lv1, 0),  L5 = __shfl(lv1, 16),
              L6 = __shfl(lv1, 32), L7 = __shfl(lv1, 48);
        if (lane == 0) {
            float nq = __fadd_rn(
                __fadd_rn(__fadd_rn(L0, L1), __fadd_rn(L2, L3)),
                __fadd_rn(__fadd_rn(L4, L5), __fadd_rn(L6, L7)));
            snq = fmaxf(__fsqrt_rn(nq), EPSV);
        }
    }
    __syncthreads();
    const float nqd = snq;

    {
        int d0 = tid * 4;
        float4 qv = *(const float4*)(qr + d0);
        float4 mv = *(const float4*)(mean + d0);
        anbuf[d0 + 0] = __fdiv_rn(__fmul_rn(qv.x, mv.x), nqd);
        anbuf[d0 + 1] = __fdiv_rn(__fmul_rn(qv.y, mv.y), nqd);
        anbuf[d0 + 2] = __fdiv_rn(__fmul_rn(qv.z, mv.z), nqd);
        anbuf[d0 + 3] = __fdiv_rn(__fmul_rn(qv.w, mv.w), nqd);
    }
    __syncthreads();

    {
        const int c = tid >> 2, chunk = tid & 3;
        const int id = candi[(size_t)b * NCAND + c];
        const int start = chunk * 320;
        const int n4 = (chunk == 3) ? 16 : 80;
        const float4* k4 = (const float4*)(knn + (size_t)id * D_DIM + start);
        const float4* a4 = (const float4*)(anbuf + start);
        float acc = 0.f;
        #pragma unroll 4
        for (int t = 0; t < n4; ++t) {
            float4 kv = k4[t];
            float4 av = a4[t];
            acc = __fmaf_rn(av.x, kv.x, acc);
            acc = __fmaf_rn(av.y, kv.y, acc);
            acc = __fmaf_rn(av.z, kv.z, acc);
            acc = __fmaf_rn(av.w, kv.w, acc);
        }
        float c2 = __shfl_down(acc, 1);
        float c3 = __shfl_down(acc, 2);
        float c4 = __shfl_down(acc, 3);
        if (chunk == 0) {
            vbuf[c] = __fadd_rn(__fadd_rn(__fadd_rn(acc, c2), c3), c4);
            ibuf[c] = id;
        }
    }
    __syncthreads();

    if (wave == 0) {
        float v = vbuf[lane];
        int id = ibuf[lane];
        float sv[TOPK]; int si[TOPK];
        #pragma unroll
        for (int s = 0; s < TOPK; ++s) {
            float bv = v; int bid = id;
            #pragma unroll
            for (int off = 32; off >= 1; off >>= 1) {
                float ov = __shfl_xor(bv, off);
                int oid = __shfl_xor(bid, off);
                if (ov > bv || (ov == bv && oid < bid)) { bv = ov; bid = oid; }
            }
            sv[s] = bv; si[s] = bid;
            if (id == bid) v = -1e30f;
        }
        if (lane == 0) {
            float m = sv[0];
            float w[TOPK];
            float ssum = 0.f;
            #pragma unroll
            for (int k = 0; k < TOPK; ++k) { w[k] = expf(sv[k] - m); ssum += w[k]; }
            float rs = 1.0f / ssum;
            #pragma unroll
            for (int k = 0; k < TOPK; ++k) {
                topw[b * TOPK + k] = w[k] * rs;
                topi[b * TOPK + k] = si[k];
            }
        }
    }
}

// ---------------- kernel F: weighted gather + outputs (frozen) --------------
__global__ void output_kernel(const float* __restrict__ topw,
                              const int* __restrict__ topi,
                              const float* __restrict__ prompts,
                              const float* __restrict__ keys,
                              float* __restrict__ out) {
    int b = blockIdx.x;
    float w[TOPK];
    int id[TOPK];
    #pragma unroll
    for (int k = 0; k < TOPK; ++k) {
        w[k] = topw[b * TOPK + k];
        id[k] = topi[b * TOPK + k];
    }

    const size_t OFF1 = (size_t)B_ROWS * D_DIM;
    const size_t OFF2 = OFF1 + (size_t)B_ROWS * TOPK;

    if (threadIdx.x < TOPK)
        out[OFF1 + (size_t)b * TOPK + threadIdx.x] = (float)id[threadIdx.x];

    int d0 = threadIdx.x * 4;
    float4 acc; acc.x = acc.y = acc.z = acc.w = 0.f;
    #pragma unroll
    for (int k = 0; k < TOPK; ++k) {
        const float* pr = prompts + (size_t)id[k] * D_DIM + d0;
        float4 pv = *(const float4*)pr;
        acc.x += w[k] * pv.x; acc.y += w[k] * pv.y;
        acc.z += w[k] * pv.z; acc.w += w[k] * pv.w;
        const float* kr = keys + (size_t)id[k] * D_DIM + d0;
        float4 kv = *(const float4*)kr;
        *(float4*)(out + OFF2 + ((size_t)b * TOPK + k) * D_DIM + d0) = kv;
    }
    *(float4*)(out + (size_t)b * D_DIM + d0) = acc;
}

// ---------------- launch ----------------
extern "C" void kernel_launch(void* const* d_in, const int* in_sizes, int n_in,
                              void* d_out, int out_size, void* d_ws, size_t ws_size,
                              hipStream_t stream) {
    const float* query   = (const float*)d_in[0];
    const float* prompts = (const float*)d_in[1];
    const float* keys    = (const float*)d_in[2];
    const float* attn    = (const float*)d_in[3];
    float* ws = (float*)d_ws;
    float* out = (float*)d_out;

    float* mean  = ws + WS_MEAN;
    float* knorm = ws + WS_KNORM;
    float* knn   = ws + WS_KNN;
    unsigned short* kn16 = (unsigned short*)(ws + WS_KN16);
    int*   candi = (int*)(ws + WS_CI);
    float* topw  = ws + WS_TW;
    int*   topi  = (int*)(ws + WS_TI);
    // aq16 scratch lives in the selected_keys output region (rewritten later
    // by output_kernel) — avoids growing d_ws.
    unsigned short* aq16 = (unsigned short*)(out + (size_t)B_ROWS * D_DIM +
                                             (size_t)B_ROWS * TOPK);

    seqmean_kernel<<<16, 256, 0, stream>>>(attn, mean);
    knorm_kernel<<<N_COMP / 4, 256, 0, stream>>>(keys, knorm);
    knn_kernel<<<N_COMP, 256, 0, stream>>>(keys, knorm, knn, kn16);
    aq16_kernel<<<8192, 256, 0, stream>>>(query, mean, aq16);
    simtop_mfma<<<512, 512, 0, stream>>>(aq16, kn16, candi);
    rescore_kernel<<<B_ROWS, 256, 0, stream>>>(query, knn, mean, candi,
                                               topw, topi);
    output_kernel<<<B_ROWS, 256, 0, stream>>>(topw, topi, prompts, keys, out);
}

// Round 11
// 951.667 us; speedup vs baseline: 8.5159x; 1.4259x over previous
//
#include <hip/hip_runtime.h>
#include <math.h>

#define D_DIM 1024
#define N_COMP 4096
#define B_ROWS 16384
#define TOPK 8
#define NC_Q 16
#define NCAND 64
#define EPSV 1e-8f

typedef __bf16 bf16x8 __attribute__((ext_vector_type(8)));
typedef float f32x4 __attribute__((ext_vector_type(4)));

// ---------------- workspace layout (in float slots) ----------------
#define WS_MEAN  0         // 1024
#define WS_KNORM 1024      // 4096
#define WS_KNN   5120      // 4096*1024 f32 (bit-exact k_n, rescore input)
#define WS_KN16  4199424   // 4096*1024 bf16 (ushort) = 2097152 float slots
#define WS_CI    6296576   // candidate idx: 16384*64 ints
#define WS_TW    7345152   // softmax weights: 16384*8
#define WS_TI    7476224   // final idx: 16384*8 ints

__device__ __forceinline__ unsigned short bf16rne(float f) {
    unsigned int u = __float_as_uint(f);
    return (unsigned short)((u + 0x7FFFu + ((u >> 16) & 1u)) >> 16);
}

__device__ __forceinline__ void gload16(const void* g, void* l) {
    __builtin_amdgcn_global_load_lds(
        (const __attribute__((address_space(1))) void*)g,
        (__attribute__((address_space(3))) void*)l, 16, 0, 0);
}

// ---------------- kernel A: np-faithful mean via LDS transpose --------------
__global__ void seqmean_kernel(const float* __restrict__ attn,
                               float* __restrict__ mean) {
    __shared__ float tile[128][65];
    const int tid = threadIdx.x;
    const int d0 = blockIdx.x * 64;
    const int c = tid & 63, r0 = tid >> 6;
    float acc = 0.f;
    for (int chunk = 0; chunk < 32; ++chunk) {
        const int base = chunk * 128;
        __syncthreads();
        #pragma unroll
        for (int rr = 0; rr < 32; ++rr) {
            int r = r0 * 32 + rr;
            tile[r][c] = attn[(size_t)(base + r) * D_DIM + d0 + c];
        }
        __syncthreads();
        if (tid < 64) {
            #pragma unroll 8
            for (int r = 0; r < 128; ++r)
                acc = __fadd_rn(acc, tile[r][tid]);
        }
    }
    if (tid < 64) mean[d0 + tid] = __fdiv_rn(acc, (float)N_COMP);
}

// ---------------- kernel B: np-faithful key norms, lane-parallel tree -------
__global__ void knorm_kernel(const float* __restrict__ keys,
                             float* __restrict__ knorm) {
    const int wave = threadIdx.x >> 6, lane = threadIdx.x & 63;
    const int n = blockIdx.x * 4 + wave;
    const float* x = keys + (size_t)n * D_DIM;
    const int l = lane & 15, g = lane >> 4;
    float lv0, lv1;
    {
        const float* xx = x + g * 128;
        float p[8];
        #pragma unroll
        for (int j = 0; j < 8; ++j) {
            float e = xx[16 * j + l];
            p[j] = __fmul_rn(e, e);
        }
        float t0 = __fadd_rn(p[0], p[1]), t1 = __fadd_rn(p[2], p[3]);
        float t2 = __fadd_rn(p[4], p[5]), t3 = __fadd_rn(p[6], p[7]);
        lv0 = __fadd_rn(__fadd_rn(t0, t1), __fadd_rn(t2, t3));
    }
    {
        const float* xx = x + (g + 4) * 128;
        float p[8];
        #pragma unroll
        for (int j = 0; j < 8; ++j) {
            float e = xx[16 * j + l];
            p[j] = __fmul_rn(e, e);
        }
        float t0 = __fadd_rn(p[0], p[1]), t1 = __fadd_rn(p[2], p[3]);
        float t2 = __fadd_rn(p[4], p[5]), t3 = __fadd_rn(p[6], p[7]);
        lv1 = __fadd_rn(__fadd_rn(t0, t1), __fadd_rn(t2, t3));
    }
    #pragma unroll
    for (int off = 8; off >= 1; off >>= 1) {
        lv0 = __fadd_rn(lv0, __shfl_down(lv0, off));
        lv1 = __fadd_rn(lv1, __shfl_down(lv1, off));
    }
    float L0 = __shfl(lv0, 0),  L1 = __shfl(lv0, 16),
          L2 = __shfl(lv0, 32), L3 = __shfl(lv0, 48);
    float L4 = __shfl(lv1, 0),  L5 = __shfl(lv1, 16),
          L6 = __shfl(lv1, 32), L7 = __shfl(lv1, 48);
    if (lane == 0) {
        float nk = __fadd_rn(
            __fadd_rn(__fadd_rn(L0, L1), __fadd_rn(L2, L3)),
            __fadd_rn(__fadd_rn(L4, L5), __fadd_rn(L6, L7)));
        knorm[n] = fmaxf(__fsqrt_rn(nk), EPSV);
    }
}

// ---------------- kernel C: knn f32 (frozen bits) + bf16 copy ---------------
__global__ void knn_kernel(const float* __restrict__ keys,
                           const float* __restrict__ knorm,
                           float* __restrict__ knn,
                           unsigned short* __restrict__ kn16) {
    int n = blockIdx.x;
    float kn = knorm[n];
    int d = threadIdx.x * 4;
    const float* row = keys + (size_t)n * D_DIM + d;
    float* orow = knn + (size_t)n * D_DIM + d;
    unsigned short* o16 = kn16 + (size_t)n * D_DIM + d;
    float r0 = __fdiv_rn(row[0], kn);
    float r1 = __fdiv_rn(row[1], kn);
    float r2 = __fdiv_rn(row[2], kn);
    float r3 = __fdiv_rn(row[3], kn);
    orow[0] = r0; orow[1] = r1; orow[2] = r2; orow[3] = r3;
    o16[0] = bf16rne(r0); o16[1] = bf16rne(r1);
    o16[2] = bf16rne(r2); o16[3] = bf16rne(r3);
}

// ---------------- kernel C2: aq16 = bf16(q * mean), precomputed -------------
__global__ void aq16_kernel(const float* __restrict__ q,
                            const float* __restrict__ mean,
                            unsigned short* __restrict__ aq16) {
    size_t i = ((size_t)blockIdx.x * 256 + threadIdx.x) * 8;
    int d = (int)(i & (D_DIM - 1));
    float4 a0 = *(const float4*)(q + i);
    float4 a1 = *(const float4*)(q + i + 4);
    float4 m0 = *(const float4*)(mean + d);
    float4 m1 = *(const float4*)(mean + d + 4);
    uint4 pk;
    pk.x = (unsigned)bf16rne(a0.x * m0.x) | ((unsigned)bf16rne(a0.y * m0.y) << 16);
    pk.y = (unsigned)bf16rne(a0.z * m0.z) | ((unsigned)bf16rne(a0.w * m0.w) << 16);
    pk.z = (unsigned)bf16rne(a1.x * m1.x) | ((unsigned)bf16rne(a1.y * m1.y) << 16);
    pk.w = (unsigned)bf16rne(a1.z * m1.z) | ((unsigned)bf16rne(a1.w * m1.w) << 16);
    *(uint4*)(aq16 + i) = pk;
}

// ---------------- kernel D: MFMA bf16 GEMM + per-quarter top-16 v2 ----------
// (R10 structure; merge now also stores the approx values -> candv.)
__global__ __launch_bounds__(512, 4) void simtop_mfma(
    const unsigned short* __restrict__ aq16,
    const unsigned short* __restrict__ kn16,
    int* __restrict__ candi, float* __restrict__ candv) {
    __shared__ __align__(16) char RAW[49152];
    uint4* A4 = (uint4*)RAW;               // [128 rows][8 slots] 16KB
    uint4* B4 = (uint4*)(RAW + 16384);     // [256 cols][8 slots] 32KB
    float* SIM = (float*)RAW;              // [64][129] overlay (epilogue)
    float* VM  = (float*)RAW;              // [256][16] overlay (merge)
    int*   IM  = (int*)(RAW + 16384);      // [256][16]

    const int tid = threadIdx.x;
    const int lane = tid & 63;
    const int wid = tid >> 6;
    const int wr = wid >> 2, wc = wid & 3;
    const int l15 = lane & 15, l4 = lane >> 4;
    const int rb = blockIdx.x >> 2;
    const int qq = blockIdx.x & 3;
    const int row0 = rb * 128;
    const int colQ = qq * 1024;
    const int srow = tid & 127;
    const int sstripe = (tid >> 7) & 1;

    float v[NC_Q]; int ix[NC_Q];
    #pragma unroll
    for (int s = 0; s < NC_Q; ++s) { v[s] = -1e30f; ix[s] = 0; }

    for (int ct = 0; ct < 4; ++ct) {
        const int col0 = colQ + ct * 256;
        f32x4 acc[4][4];
        #pragma unroll
        for (int i = 0; i < 4; ++i)
            #pragma unroll
            for (int j = 0; j < 4; ++j) {
                acc[i][j][0] = 0.f; acc[i][j][1] = 0.f;
                acc[i][j][2] = 0.f; acc[i][j][3] = 0.f;
            }

        for (int kt = 0; kt < 16; ++kt) {
            const int k0 = kt * 64;
            __syncthreads();
            #pragma unroll
            for (int c = 0; c < 2; ++c) {
                int unit = c * 512 + tid;
                int r = unit >> 3, j = unit & 7;
                gload16(aq16 + (size_t)(row0 + r) * D_DIM + k0 + (j ^ (r & 7)) * 8,
                        (char*)A4 + unit * 16);
            }
            #pragma unroll
            for (int c = 0; c < 4; ++c) {
                int unit = c * 512 + tid;
                int r = unit >> 3, j = unit & 7;
                gload16(kn16 + (size_t)(col0 + r) * D_DIM + k0 + (j ^ (r & 7)) * 8,
                        (char*)B4 + unit * 16);
            }
            __syncthreads();
            #pragma unroll
            for (int kk = 0; kk < 2; ++kk) {
                bf16x8 af[4], bfv[4];
                #pragma unroll
                for (int f = 0; f < 4; ++f) {
                    int rowa = wr * 64 + f * 16 + l15;
                    int slot = kk * 4 + l4;
                    af[f] = __builtin_bit_cast(bf16x8,
                              A4[rowa * 8 + (slot ^ (rowa & 7))]);
                    int rowb = wc * 64 + f * 16 + l15;
                    bfv[f] = __builtin_bit_cast(bf16x8,
                              B4[rowb * 8 + (slot ^ (rowb & 7))]);
                }
                #pragma unroll
                for (int i = 0; i < 4; ++i)
                    #pragma unroll
                    for (int j = 0; j < 4; ++j)
                        acc[i][j] = __builtin_amdgcn_mfma_f32_16x16x32_bf16(
                            af[i], bfv[j], acc[i][j], 0, 0, 0);
            }
        }
        #pragma unroll 1
        for (int p = 0; p < 4; ++p) {
            __syncthreads();
            if (wr == (p >> 1) && (wc >> 1) == (p & 1)) {
                #pragma unroll
                for (int i = 0; i < 4; ++i)
                    #pragma unroll
                    for (int j = 0; j < 4; ++j)
                        #pragma unroll
                        for (int rg = 0; rg < 4; ++rg)
                            SIM[(i * 16 + l4 * 4 + rg) * 129 +
                                (wc & 1) * 64 + j * 16 + l15] = acc[i][j][rg];
            }
            __syncthreads();
            if (tid < 256 && (srow >> 6) == (p >> 1)) {
                const float* rp = SIM + (srow & 63) * 129 + sstripe * 64;
                const int gbase = col0 + (p & 1) * 128 + sstripe * 64;
                #pragma unroll 1
                for (int cc = 0; cc < 64; ++cc) {
                    float cv = rp[cc];
                    if (cv > v[NC_Q - 1]) {
                        v[NC_Q - 1] = cv; ix[NC_Q - 1] = gbase + cc;
                        #pragma unroll
                        for (int s = NC_Q - 1; s > 0; --s)
                            if (v[s] > v[s - 1]) {
                                float tv = v[s]; v[s] = v[s - 1]; v[s - 1] = tv;
                                int ti = ix[s]; ix[s] = ix[s - 1]; ix[s - 1] = ti;
                            }
                    }
                }
            }
        }
    }
    __syncthreads();
    if (tid < 256) {
        #pragma unroll
        for (int s = 0; s < NC_Q; ++s) {
            VM[tid * 16 + s] = v[s];
            IM[tid * 16 + s] = ix[s];
        }
    }
    __syncthreads();
    if (tid < 128) {     // merge two sorted stripe lists -> top-16 + values
        int ia = 0, ib = 0;
        #pragma unroll 1
        for (int s = 0; s < NC_Q; ++s) {
            float va = (ia < 16) ? VM[tid * 16 + ia] : -3e38f;
            float vb = (ib < 16) ? VM[(tid + 128) * 16 + ib] : -3e38f;
            int id; float vv;
            if (va >= vb) { id = IM[tid * 16 + ia]; vv = va; ++ia; }
            else          { id = IM[(tid + 128) * 16 + ib]; vv = vb; ++ib; }
            candi[(size_t)(row0 + tid) * NCAND + qq * 16 + s] = id;
            candv[(size_t)(row0 + tid) * NCAND + qq * 16 + s] = vv;
        }
    }
}

// ---------------- kernel E: sparse bit-faithful KC=320 rescore --------------
// Exact-rescore only candidates whose bf16-approx value is within a safe
// margin of the approx 8th-best. Margin = 0.003*||aq|| (~60 sigma of the
// bf16 dot noise; hard C-S bound 2^-8*||aq|| per side).
__global__ __launch_bounds__(256) void rescore_kernel(
    const float* __restrict__ q, const float* __restrict__ knn,
    const float* __restrict__ mean, const int* __restrict__ candi,
    const float* __restrict__ candv,
    float* __restrict__ topw, int* __restrict__ topi) {
    __shared__ float anbuf[D_DIM];
    __shared__ float vbuf[NCAND];
    __shared__ int ibuf[NCAND];
    __shared__ int selid[NCAND];
    __shared__ float snq;
    __shared__ int m_s;
    const int tid = threadIdx.x;
    const int wave = tid >> 6, lane = tid & 63;
    const int b = blockIdx.x;
    const float* qr = q + (size_t)b * D_DIM;

    // ---- wave 0: numpy pairwise norm tree (frozen bits) ----
    if (wave == 0) {
        const int l = lane & 15, g = lane >> 4;
        float lv0, lv1;
        {
            const float* x = qr + g * 128;
            const float* m = mean + g * 128;
            float p[8];
            #pragma unroll
            for (int j = 0; j < 8; ++j) {
                float e = __fmul_rn(x[16 * j + l], m[16 * j + l]);
                p[j] = __fmul_rn(e, e);
            }
            float t0 = __fadd_rn(p[0], p[1]), t1 = __fadd_rn(p[2], p[3]);
            float t2 = __fadd_rn(p[4], p[5]), t3 = __fadd_rn(p[6], p[7]);
            lv0 = __fadd_rn(__fadd_rn(t0, t1), __fadd_rn(t2, t3));
        }
        {
            const float* x = qr + (g + 4) * 128;
            const float* m = mean + (g + 4) * 128;
            float p[8];
            #pragma unroll
            for (int j = 0; j < 8; ++j) {
                float e = __fmul_rn(x[16 * j + l], m[16 * j + l]);
                p[j] = __fmul_rn(e, e);
            }
            float t0 = __fadd_rn(p[0], p[1]), t1 = __fadd_rn(p[2], p[3]);
            float t2 = __fadd_rn(p[4], p[5]), t3 = __fadd_rn(p[6], p[7]);
            lv1 = __fadd_rn(__fadd_rn(t0, t1), __fadd_rn(t2, t3));
        }
        #pragma unroll
        for (int off = 8; off >= 1; off >>= 1) {
            lv0 = __fadd_rn(lv0, __shfl_down(lv0, off));
            lv1 = __fadd_rn(lv1, __shfl_down(lv1, off));
        }
        float L0 = __shfl(lv0, 0),  L1 = __shfl(lv0, 16),
              L2 = __shfl(lv0, 32), L3 = __shfl(lv0, 48);
        float L4 = __shfl(lv1, 0),  L5 = __shfl(lv1, 16),
              L6 = __shfl(lv1, 32), L7 = __shfl(lv1, 48);
        if (lane == 0) {
            float nq = __fadd_rn(
                __fadd_rn(__fadd_rn(L0, L1), __fadd_rn(L2, L3)),
                __fadd_rn(__fadd_rn(L4, L5), __fadd_rn(L6, L7)));
            snq = fmaxf(__fsqrt_rn(nq), EPSV);
        }
    }
    __syncthreads();
    const float nqd = snq;

    // ---- all threads: materialize f32 aq_n (frozen bits) ----
    {
        int d0 = tid * 4;
        float4 qv = *(const float4*)(qr + d0);
        float4 mv = *(const float4*)(mean + d0);
        anbuf[d0 + 0] = __fdiv_rn(__fmul_rn(qv.x, mv.x), nqd);
        anbuf[d0 + 1] = __fdiv_rn(__fmul_rn(qv.y, mv.y), nqd);
        anbuf[d0 + 2] = __fdiv_rn(__fmul_rn(qv.z, mv.z), nqd);
        anbuf[d0 + 3] = __fdiv_rn(__fmul_rn(qv.w, mv.w), nqd);
    }

    // ---- wave 1: approx t8 + threshold selection + compaction ----
    if (wave == 1) {
        float av = candv[(size_t)b * NCAND + lane];
        int aid = candi[(size_t)b * NCAND + lane];
        // 8-pass knockout for the approx 8th-best value
        float t8;
        {
            float vv = av; int vid = aid;
            #pragma unroll
            for (int s = 0; s < TOPK; ++s) {
                float bv = vv; int bid = vid;
                #pragma unroll
                for (int off = 32; off >= 1; off >>= 1) {
                    float ov = __shfl_xor(bv, off);
                    int oid = __shfl_xor(bid, off);
                    if (ov > bv || (ov == bv && oid < bid)) { bv = ov; bid = oid; }
                }
                t8 = bv;
                if (vid == bid) vv = -1e30f;
            }
        }
        float thr = t8 - 0.003f * nqd;
        bool sel = (av >= thr);
        unsigned long long mk = __ballot(sel);
        int pos = __popcll(mk & ((1ull << lane) - 1ull));
        if (sel) selid[pos] = aid;
        if (lane == 0) m_s = (int)__popcll(mk);
    }
    __syncthreads();
    const int m = m_s;

    // ---- sparse exact rescore: tid = s*4 + chunk, s < m ----
    {
        const int s = tid >> 2, chunk = tid & 3;
        if (s < m) {
            const int id = selid[s];
            const int start = chunk * 320;
            const int n4 = (chunk == 3) ? 16 : 80;
            const float4* k4 = (const float4*)(knn + (size_t)id * D_DIM + start);
            const float4* a4 = (const float4*)(anbuf + start);
            float acc = 0.f;
            #pragma unroll 4
            for (int t = 0; t < n4; ++t) {
                float4 kv = k4[t];
                float4 av4 = a4[t];
                acc = __fmaf_rn(av4.x, kv.x, acc);
                acc = __fmaf_rn(av4.y, kv.y, acc);
                acc = __fmaf_rn(av4.z, kv.z, acc);
                acc = __fmaf_rn(av4.w, kv.w, acc);
            }
            float c2 = __shfl_down(acc, 1);
            float c3 = __shfl_down(acc, 2);
            float c4 = __shfl_down(acc, 3);
            if (chunk == 0) {
                vbuf[s] = __fadd_rn(__fadd_rn(__fadd_rn(acc, c2), c3), c4);
                ibuf[s] = id;
            }
        }
    }
    __syncthreads();

    // ---- wave 0: exact top-8 knockout + softmax (frozen math) ----
    if (wave == 0) {
        float v = (lane < m) ? vbuf[lane] : -3e38f;
        int id = (lane < m) ? ibuf[lane] : 0x7fffffff;
        float sv[TOPK]; int si[TOPK];
        #pragma unroll
        for (int s = 0; s < TOPK; ++s) {
            float bv = v; int bid = id;
            #pragma unroll
            for (int off = 32; off >= 1; off >>= 1) {
                float ov = __shfl_xor(bv, off);
                int oid = __shfl_xor(bid, off);
                if (ov > bv || (ov == bv && oid < bid)) { bv = ov; bid = oid; }
            }
            sv[s] = bv; si[s] = bid;
            if (id == bid) v = -3e38f;
        }
        if (lane == 0) {
            float mx = sv[0];
            float w[TOPK];
            float ssum = 0.f;
            #pragma unroll
            for (int k = 0; k < TOPK; ++k) { w[k] = expf(sv[k] - mx); ssum += w[k]; }
            float rs = 1.0f / ssum;
            #pragma unroll
            for (int k = 0; k < TOPK; ++k) {
                topw[b * TOPK + k] = w[k] * rs;
                topi[b * TOPK + k] = si[k];
            }
        }
    }
}

// ---------------- kernel F: weighted gather + outputs (frozen) --------------
__global__ void output_kernel(const float* __restrict__ topw,
                              const int* __restrict__ topi,
                              const float* __restrict__ prompts,
                              const float* __restrict__ keys,
                              float* __restrict__ out) {
    int b = blockIdx.x;
    float w[TOPK];
    int id[TOPK];
    #pragma unroll
    for (int k = 0; k < TOPK; ++k) {
        w[k] = topw[b * TOPK + k];
        id[k] = topi[b * TOPK + k];
    }

    const size_t OFF1 = (size_t)B_ROWS * D_DIM;
    const size_t OFF2 = OFF1 + (size_t)B_ROWS * TOPK;

    if (threadIdx.x < TOPK)
        out[OFF1 + (size_t)b * TOPK + threadIdx.x] = (float)id[threadIdx.x];

    int d0 = threadIdx.x * 4;
    float4 acc; acc.x = acc.y = acc.z = acc.w = 0.f;
    #pragma unroll
    for (int k = 0; k < TOPK; ++k) {
        const float* pr = prompts + (size_t)id[k] * D_DIM + d0;
        float4 pv = *(const float4*)pr;
        acc.x += w[k] * pv.x; acc.y += w[k] * pv.y;
        acc.z += w[k] * pv.z; acc.w += w[k] * pv.w;
        const float* kr = keys + (size_t)id[k] * D_DIM + d0;
        float4 kv = *(const float4*)kr;
        *(float4*)(out + OFF2 + ((size_t)b * TOPK + k) * D_DIM + d0) = kv;
    }
    *(float4*)(out + (size_t)b * D_DIM + d0) = acc;
}

// ---------------- launch ----------------
extern "C" void kernel_launch(void* const* d_in, const int* in_sizes, int n_in,
                              void* d_out, int out_size, void* d_ws, size_t ws_size,
                              hipStream_t stream) {
    const float* query   = (const float*)d_in[0];
    const float* prompts = (const float*)d_in[1];
    const float* keys    = (const float*)d_in[2];
    const float* attn    = (const float*)d_in[3];
    float* ws = (float*)d_ws;
    float* out = (float*)d_out;

    float* mean  = ws + WS_MEAN;
    float* knorm = ws + WS_KNORM;
    float* knn   = ws + WS_KNN;
    unsigned short* kn16 = (unsigned short*)(ws + WS_KN16);
    int*   candi = (int*)(ws + WS_CI);
    float* topw  = ws + WS_TW;
    int*   topi  = (int*)(ws + WS_TI);
    // scratch in the selected_keys output region (rewritten by output_kernel):
    // aq16: 16M ushorts = 8388608 float slots; candv: 16384*64 floats after it.
    float* outscratch = out + (size_t)B_ROWS * D_DIM + (size_t)B_ROWS * TOPK;
    unsigned short* aq16 = (unsigned short*)outscratch;
    float* candv = outscratch + 8388608;

    seqmean_kernel<<<16, 256, 0, stream>>>(attn, mean);
    knorm_kernel<<<N_COMP / 4, 256, 0, stream>>>(keys, knorm);
    knn_kernel<<<N_COMP, 256, 0, stream>>>(keys, knorm, knn, kn16);
    aq16_kernel<<<8192, 256, 0, stream>>>(query, mean, aq16);
    simtop_mfma<<<512, 512, 0, stream>>>(aq16, kn16, candi, candv);
    rescore_kernel<<<B_ROWS, 256, 0, stream>>>(query, knn, mean, candi, candv,
                                               topw, topi);
    output_kernel<<<B_ROWS, 256, 0, stream>>>(topw, topi, prompts, keys, out);
}